// Round 9
// baseline (359.381 us; speedup 1.0000x reference)
//
#include <hip/hip_runtime.h>
#include <stdint.h>

#define T_LEN 4096
#define N_ROWS 4096
#define N_ELEM (4096u * 4096u)
#define PD(i) ((i) + ((i) >> 5))

// ---------------- wavelet filters (db4) ----------------
__constant__ float c_DEC_LO[8] = {
  -0.010597401785069032f, 0.0328830116668852f, 0.030841381835560764f,
  -0.18703481171909309f, -0.027983769416859854f, 0.6308807679298589f,
   0.7148465705529157f, 0.2303778133088965f };
__constant__ float c_DEC_HI[8] = {
  -0.2303778133088965f, 0.7148465705529157f, -0.6308807679298589f,
  -0.027983769416859854f, 0.18703481171909309f, 0.030841381835560764f,
  -0.0328830116668852f, -0.010597401785069032f };

#define RL0 0.2303778133088965f
#define RL1 0.7148465705529157f
#define RL2 0.6308807679298589f
#define RL3 (-0.027983769416859854f)
#define RL4 (-0.18703481171909309f)
#define RL5 0.030841381835560764f
#define RL6 0.0328830116668852f
#define RL7 (-0.010597401785069032f)
#define RH0 (-0.010597401785069032f)
#define RH1 (-0.0328830116668852f)
#define RH2 0.030841381835560764f
#define RH3 0.18703481171909309f
#define RH4 (-0.027983769416859854f)
#define RH5 (-0.6308807679298589f)
#define RH6 0.7148465705529157f
#define RH7 (-0.2303778133088965f)

// ---------------- Threefry-2x32 (host+device) ----------------
__host__ __device__ __forceinline__ uint32_t rotl32(uint32_t v, int r) {
  return (v << r) | (v >> (32 - r));
}

__host__ __device__ __forceinline__ void tf2x32(uint32_t k0, uint32_t k1,
                                                uint32_t c0, uint32_t c1,
                                                uint32_t& o0, uint32_t& o1) {
  uint32_t ks2 = k0 ^ k1 ^ 0x1BD11BDAu;
  uint32_t x0 = c0 + k0;
  uint32_t x1 = c1 + k1;
#define TFR(r) { x0 += x1; x1 = rotl32(x1, r); x1 ^= x0; }
  TFR(13) TFR(15) TFR(26) TFR(6)
  x0 += k1;  x1 += ks2 + 1u;
  TFR(17) TFR(29) TFR(16) TFR(24)
  x0 += ks2; x1 += k0 + 2u;
  TFR(13) TFR(15) TFR(26) TFR(6)
  x0 += k0;  x1 += k1 + 3u;
  TFR(17) TFR(29) TFR(16) TFR(24)
  x0 += k1;  x1 += ks2 + 4u;
  TFR(13) TFR(15) TFR(26) TFR(6)
  x0 += ks2; x1 += k0 + 5u;
#undef TFR
  o0 = x0; o1 = x1;
}

__host__ __device__ __forceinline__ uint32_t jbits_scalar(uint32_t kx, uint32_t ky) {
  uint32_t a, b; tf2x32(kx, ky, 0u, 0u, a, b);
  return a ^ b;
}

__device__ __forceinline__ uint32_t jbits_elem(uint32_t kx, uint32_t ky, uint32_t i) {
  uint32_t a, b; tf2x32(kx, ky, 0u, i, a, b); return a ^ b;
}

__host__ __device__ __forceinline__ float junif_scalar(uint32_t kx, uint32_t ky) {
  union { uint32_t u; float f; } cv;
  cv.u = (jbits_scalar(kx, ky) >> 9) | 0x3f800000u;
  return cv.f - 1.0f;
}

__host__ __device__ __forceinline__ void jsplit2(uint32_t kx, uint32_t ky, uint32_t* o) {
  tf2x32(kx, ky, 0u, 0u, o[0], o[1]);
  tf2x32(kx, ky, 0u, 1u, o[2], o[3]);
}

__host__ __device__ __forceinline__ void jsplit4(uint32_t kx, uint32_t ky, uint32_t* o) {
  tf2x32(kx, ky, 0u, 0u, o[0], o[1]);
  tf2x32(kx, ky, 0u, 1u, o[2], o[3]);
  tf2x32(kx, ky, 0u, 2u, o[4], o[5]);
  tf2x32(kx, ky, 0u, 3u, o[6], o[7]);
}

__host__ __device__ __forceinline__ int jrandint(uint32_t kx, uint32_t ky, uint32_t span) {
  uint32_t c[4];
  jsplit2(kx, ky, c);
  uint32_t hi = jbits_scalar(c[0], c[1]);
  uint32_t lo = jbits_scalar(c[2], c[3]);
  uint32_t mult = 65536u % span;
  mult = (mult * mult) % span;
  uint32_t off = ((hi % span) * mult + (lo % span)) % span;
  return (int)off;
}

__host__ __device__ void distort_params(uint32_t kx, uint32_t ky,
                                        int* f0, int* af, int* t0, int* at) {
  uint32_t q[8];
  jsplit4(kx, ky, q);
  *af = junif_scalar(q[0], q[1]) < 0.3f;
  *f0 = jrandint(q[2], q[3], 3687u);
  *at = junif_scalar(q[4], q[5]) < 0.3f;
  *t0 = jrandint(q[6], q[7], 3892u);
}

__device__ __forceinline__ float erfinv32(float x) {
  float w = -log1pf(-x * x);
  float p;
  if (w < 5.0f) {
    w = w - 2.5f;
    p = 2.81022636e-08f;
    p = fmaf(p, w, 3.43273939e-07f);
    p = fmaf(p, w, -3.5233877e-06f);
    p = fmaf(p, w, -4.39150654e-06f);
    p = fmaf(p, w, 0.00021858087f);
    p = fmaf(p, w, -0.00125372503f);
    p = fmaf(p, w, -0.00417768164f);
    p = fmaf(p, w, 0.246640727f);
    p = fmaf(p, w, 1.50140941f);
  } else {
    w = sqrtf(w) - 3.0f;
    p = -0.000200214257f;
    p = fmaf(p, w, 0.000100950558f);
    p = fmaf(p, w, 0.00134934322f);
    p = fmaf(p, w, -0.00367342844f);
    p = fmaf(p, w, 0.00573950773f);
    p = fmaf(p, w, -0.0076224613f);
    p = fmaf(p, w, 0.00943887047f);
    p = fmaf(p, w, 1.00167406f);
    p = fmaf(p, w, 2.83297682f);
  }
  return p * x;
}

__device__ __forceinline__ float jax_normal_from_bits(uint32_t bits) {
  union { uint32_t u; float f; } cv;
  cv.u = (bits >> 9) | 0x3f800000u;
  float f = cv.f - 1.0f;
  const float lo = -0.99999994f;
  float u = __fadd_rn(__fmul_rn(f, 2.0f), lo);
  u = fmaxf(lo, u);
  return 1.41421356f * erfinv32(u);
}

// numpy tree-of-8 sum
__device__ __forceinline__ float tree8(const float* p) {
  return __fadd_rn(
      __fadd_rn(__fadd_rn(p[0], p[1]), __fadd_rn(p[2], p[3])),
      __fadd_rn(__fadd_rn(p[4], p[5]), __fadd_rn(p[6], p[7])));
}

// ---------------- wavelet steps (bit-exact vs rounds 6-8) ----------------
__device__ void dwt_step(const float* a, int n, float* oa, float* od, int nOut, int tid) {
  int iHi = (n - 2) >> 1;
  for (int i = tid; i < nOut; i += 256) {
    int base = 2 * i - 6;
    float pa[8], pd[8];
    if (i >= 3 && i <= iHi) {
      #pragma unroll
      for (int j = 0; j < 8; ++j) {
        float xv = a[base + j];
        pa[j] = __fmul_rn(c_DEC_LO[7 - j], xv);
        pd[j] = __fmul_rn(c_DEC_HI[7 - j], xv);
      }
    } else {
      #pragma unroll
      for (int j = 0; j < 8; ++j) {
        int q = base + j;
        q = (q < 0) ? (-q - 1) : ((q >= n) ? (2 * n - 1 - q) : q);
        float xv = a[q];
        pa[j] = __fmul_rn(c_DEC_LO[7 - j], xv);
        pd[j] = __fmul_rn(c_DEC_HI[7 - j], xv);
      }
    }
    oa[i] = tree8(pa);
    od[i] = tree8(pd);
  }
}

__device__ void idwt_step(const float* __restrict__ a, const float* __restrict__ d,
                          int m, float* __restrict__ out, int nOut, float thr,
                          bool trA, int tid) {
  for (int t = tid; t < nOut; t += 256) {
    int odd = t & 1;
    int h0 = (t - odd) >> 1;
    float a0 = a[h0], a1 = a[h0 + 1], a2 = a[h0 + 2], a3 = a[h0 + 3];
    if (trA) {
      a0 = (fabsf(a0) < thr) ? 0.f : a0;
      a1 = (fabsf(a1) < thr) ? 0.f : a1;
      a2 = (fabsf(a2) < thr) ? 0.f : a2;
      a3 = (fabsf(a3) < thr) ? 0.f : a3;
    }
    float d0 = d[h0], d1 = d[h0 + 1], d2 = d[h0 + 2], d3 = d[h0 + 3];
    d0 = (fabsf(d0) < thr) ? 0.f : d0;
    d1 = (fabsf(d1) < thr) ? 0.f : d1;
    d2 = (fabsf(d2) < thr) ? 0.f : d2;
    d3 = (fabsf(d3) < thr) ? 0.f : d3;
    float cl0 = odd ? RL7 : RL6, cl1 = odd ? RL5 : RL4;
    float cl2 = odd ? RL3 : RL2, cl3 = odd ? RL1 : RL0;
    float ch0 = odd ? RH7 : RH6, ch1 = odd ? RH5 : RH4;
    float ch2 = odd ? RH3 : RH2, ch3 = odd ? RH1 : RH0;
    float sa = __fadd_rn(__fadd_rn(__fmul_rn(cl0, a0), __fmul_rn(cl1, a1)),
                         __fadd_rn(__fmul_rn(cl2, a2), __fmul_rn(cl3, a3)));
    float sd = __fadd_rn(__fadd_rn(__fmul_rn(ch0, d0), __fmul_rn(ch1, d1)),
                         __fadd_rn(__fmul_rn(ch2, d2), __fmul_rn(ch3, d3)));
    out[t] = __fadd_rn(sa, sd);
  }
}

__device__ void np_pw262_partials(const float* src, float* pbuf, int tid) {
  if (tid < 24) {
    int blk = tid >> 3, k = tid & 7;
    const float* base = src + (blk == 0 ? 0 : (blk == 1 ? 128 : 192));
    int iters = (blk == 0 ? 16 : 8);
    float r = base[k];
    for (int it = 1; it < iters; ++it) r = __fadd_rn(r, base[8 * it + k]);
    pbuf[tid] = r;
  }
}

__device__ float np_pw262_combine(const float* src, const float* pbuf) {
  float b0 = tree8(pbuf + 0);
  float b1 = tree8(pbuf + 8);
  float b2 = tree8(pbuf + 16);
  for (int i = 256; i < 262; ++i) b2 = __fadd_rn(b2, src[i]);
  return __fadd_rn(b0, __fadd_rn(b1, b2));
}

// ---------------- role 0: wavelet (o0, o1, o4[; fused mask+noise]) ----------
__device__ void wavelet_row(float* smem, const float* __restrict__ x,
                            float* __restrict__ out0, float* __restrict__ out1,
                            float* __restrict__ out4, int row,
                            int fuse, int at_c, int t0_c, uint32_t kcx, uint32_t kcy) {
  float* A  = smem;
  float* B  = smem + 4096;
  float* D1 = smem + 6147;
  float* D2 = smem + 8198;
  float* D3 = smem + 9227;
  float* D4 = smem + 9745;
  float* SC = smem + 10007;
  float* Bp = B + 512;
  const int tid = threadIdx.x;
  const float4* s4 = reinterpret_cast<const float4*>(x + (size_t)row * T_LEN);
  float4* o04 = reinterpret_cast<float4*>(out0 + (size_t)row * T_LEN);
  #pragma unroll
  for (int k = 0; k < 4; ++k) {
    float4 v = s4[tid + (k << 8)];
    *reinterpret_cast<float4*>(&A[4 * (tid + (k << 8))]) = v;
    o04[tid + (k << 8)] = v;
  }
  __syncthreads();
  dwt_step(A, 4096, B, D1, 2051, tid); __syncthreads();
  dwt_step(B, 2051, A, D2, 1029, tid); __syncthreads();
  dwt_step(A, 1029, B, D3, 518, tid);  __syncthreads();
  dwt_step(B, 518, A, D4, 262, tid);   __syncthreads();

  np_pw262_partials(A, Bp, tid);
  __syncthreads();
  if (tid == 0) SC[0] = np_pw262_combine(A, Bp) / 262.0f;
  __syncthreads();
  float mu = SC[0];
  for (int i = tid; i < 262; i += 256) {
    float dv = __fsub_rn(A[i], mu);
    B[i] = __fmul_rn(dv, dv);
  }
  __syncthreads();
  np_pw262_partials(B, Bp, tid);
  __syncthreads();
  if (tid == 0) SC[1] = __fsqrt_rn(np_pw262_combine(B, Bp) / 262.0f);
  __syncthreads();
  float sigma = SC[1];

  float ra0 = A[tid];
  float ra1 = (tid < 6) ? A[256 + tid] : 0.f;

  #pragma unroll
  for (int v = 0; v < 2; ++v) {
    if (v == 1) {
      __syncthreads();
      A[tid] = ra0;
      if (tid < 6) A[256 + tid] = ra1;
      __syncthreads();
    }
    float thr = __fmul_rn((v == 0 ? 0.5f : 0.25f), sigma);
    idwt_step(A, D4, 262, B, 518, thr, true, tid);    __syncthreads();
    idwt_step(B, D3, 518, A, 1029, thr, false, tid);  __syncthreads();
    idwt_step(A, D2, 1029, B, 2051, thr, false, tid); __syncthreads();
    idwt_step(B, D1, 2051, A, 4096, thr, false, tid); __syncthreads();
    if (v == 0) {
      float4* dst4 = reinterpret_cast<float4*>(out1 + (size_t)row * T_LEN);
      #pragma unroll
      for (int k = 0; k < 4; ++k)
        dst4[tid + (k << 8)] = *reinterpret_cast<const float4*>(&A[4 * (tid + (k << 8))]);
    }
  }

  float4* dst4 = reinterpret_cast<float4*>(out4 + (size_t)row * T_LEN);
  if (!fuse) {
    #pragma unroll
    for (int k = 0; k < 4; ++k)
      dst4[tid + (k << 8)] = *reinterpret_cast<const float4*>(&A[4 * (tid + (k << 8))]);
    return;
  }

  float w[16];
  #pragma unroll
  for (int k = 0; k < 4; ++k) {
    float4 vv = *reinterpret_cast<const float4*>(&A[4 * (tid + (k << 8))]);
    w[4 * k + 0] = vv.x; w[4 * k + 1] = vv.y; w[4 * k + 2] = vv.z; w[4 * k + 3] = vv.w;
  }
  if (at_c) {
    #pragma unroll
    for (int i = 0; i < 16; ++i) {
      int col = 4 * (tid + ((i >> 2) << 8)) + (i & 3);
      if (col >= t0_c && col < t0_c + 204) w[i] *= 0.1f;
    }
  }
  __syncthreads();
  float* red = B;
  float acc = 0.f;
  #pragma unroll
  for (int i = 0; i < 16; ++i) acc += w[i];
  red[tid] = acc; __syncthreads();
  for (int o = 128; o > 0; o >>= 1) { if (tid < o) red[tid] += red[tid + o]; __syncthreads(); }
  float nmu = red[0] * (1.0f / 4096.0f);
  __syncthreads();
  acc = 0.f;
  #pragma unroll
  for (int i = 0; i < 16; ++i) { float dv = w[i] - nmu; acc += dv * dv; }
  red[tid] = acc; __syncthreads();
  for (int o = 128; o > 0; o >>= 1) { if (tid < o) red[tid] += red[tid + o]; __syncthreads(); }
  float nsig = sqrtf(red[0] / 4095.0f);

  #pragma unroll
  for (int k = 0; k < 4; ++k) {
    float o[4];
    #pragma unroll
    for (int c = 0; c < 4; ++c) {
      uint32_t col = (uint32_t)(4 * (tid + (k << 8)) + c);
      uint32_t idx = ((uint32_t)row << 12) + col;
      float z = jax_normal_from_bits(jbits_elem(kcx, kcy, idx));
      o[c] = w[4 * k + c] + __fmul_rn(__fmul_rn(z, 0.02f), nsig);
    }
    dst4[tid + (k << 8)] = make_float4(o[0], o[1], o[2], o[3]);
  }
}

// ---------------- role 1: radix-4 FFT distort -> o2 ----------------
__constant__ int c_STW_OFF[6] = {0, 1024, 1280, 1344, 1360, 1364};

__device__ void fft_distort_row(float* smem, const float* __restrict__ src,
                                float* __restrict__ dst, int row,
                                int af, int f0, int at, int t0) {
  float* RE = smem;
  float* IM = smem + 4224;
  float2* STW = (float2*)(smem + 8448);
  const int tid = threadIdx.x;

  const float4* s4 = reinterpret_cast<const float4*>(src + (size_t)row * T_LEN);
  float4 v4[4];
  #pragma unroll
  for (int k = 0; k < 4; ++k) v4[k] = s4[tid + (k << 8)];

  float w[16];
  if (af) {
    for (int t = tid; t < 1365; t += 256) {
      int s, j;
      if (t < 1024) { s = 0; j = t; }
      else if (t < 1280) { s = 1; j = t - 1024; }
      else if (t < 1344) { s = 2; j = t - 1280; }
      else if (t < 1360) { s = 3; j = t - 1344; }
      else if (t < 1364) { s = 4; j = t - 1360; }
      else { s = 5; j = 0; }
      int e = j << (2 * s);
      float ang = (float)e * (-1.5339807878856412e-3f);
      float sn, cs;
      __sincosf(ang, &sn, &cs);
      STW[t] = make_float2(cs, sn);
    }
    #pragma unroll
    for (int k = 0; k < 4; ++k) {
      int p = 4 * (tid + (k << 8));
      RE[PD(p + 0)] = v4[k].x; IM[PD(p + 0)] = 0.f;
      RE[PD(p + 1)] = v4[k].y; IM[PD(p + 1)] = 0.f;
      RE[PD(p + 2)] = v4[k].z; IM[PD(p + 2)] = 0.f;
      RE[PD(p + 3)] = v4[k].w; IM[PD(p + 3)] = 0.f;
    }
    __syncthreads();
    for (int s = 0; s < 6; ++s) {
      int Lsh = 12 - 2 * s, Qsh = Lsh - 2, Qm = (1 << Qsh) - 1, off = c_STW_OFF[s];
      for (int b = tid; b < 1024; b += 256) {
        int j = b & Qm, g = b >> Qsh;
        int i0 = (g << Lsh) + j;
        int i1 = i0 + (1 << Qsh), i2 = i1 + (1 << Qsh), i3 = i2 + (1 << Qsh);
        float x0r = RE[PD(i0)], x0i = IM[PD(i0)];
        float x1r = RE[PD(i1)], x1i = IM[PD(i1)];
        float x2r = RE[PD(i2)], x2i = IM[PD(i2)];
        float x3r = RE[PD(i3)], x3i = IM[PD(i3)];
        float t0r = x0r + x2r, t0i = x0i + x2i;
        float t1r = x0r - x2r, t1i = x0i - x2i;
        float t2r = x1r + x3r, t2i = x1i + x3i;
        float t3r = x1r - x3r, t3i = x1i - x3i;
        float2 w1 = STW[off + j];
        float c1 = w1.x, s1 = w1.y;
        float c2 = c1 * c1 - s1 * s1, s2 = 2.f * c1 * s1;
        float c3 = c1 * c2 - s1 * s2, s3 = c1 * s2 + s1 * c2;
        RE[PD(i0)] = t0r + t2r; IM[PD(i0)] = t0i + t2i;
        float u1r = t1r + t3i, u1i = t1i - t3r;
        RE[PD(i1)] = u1r * c1 - u1i * s1; IM[PD(i1)] = u1r * s1 + u1i * c1;
        float u2r = t0r - t2r, u2i = t0i - t2i;
        RE[PD(i2)] = u2r * c2 - u2i * s2; IM[PD(i2)] = u2r * s2 + u2i * c2;
        float u3r = t1r - t3i, u3i = t1i + t3r;
        RE[PD(i3)] = u3r * c3 - u3i * s3; IM[PD(i3)] = u3r * s3 + u3i * c3;
      }
      __syncthreads();
    }
    for (int p = tid; p < 4096; p += 256) {
      uint32_t rb = __brev((uint32_t)p) >> 20;
      int kk = (int)(((rb & 0x555u) << 1) | ((rb >> 1) & 0x555u));
      if (kk >= f0 && kk < f0 + 409) { RE[PD(p)] *= 0.1f; IM[PD(p)] *= 0.1f; }
    }
    __syncthreads();
    for (int s = 5; s >= 0; --s) {
      int Lsh = 12 - 2 * s, Qsh = Lsh - 2, Qm = (1 << Qsh) - 1, off = c_STW_OFF[s];
      for (int b = tid; b < 1024; b += 256) {
        int j = b & Qm, g = b >> Qsh;
        int i0 = (g << Lsh) + j;
        int i1 = i0 + (1 << Qsh), i2 = i1 + (1 << Qsh), i3 = i2 + (1 << Qsh);
        float y0r = RE[PD(i0)], y0i = IM[PD(i0)];
        float y1r = RE[PD(i1)], y1i = IM[PD(i1)];
        float y2r = RE[PD(i2)], y2i = IM[PD(i2)];
        float y3r = RE[PD(i3)], y3i = IM[PD(i3)];
        float2 w1 = STW[off + j];
        float c1 = w1.x, s1 = -w1.y;
        float c2 = c1 * c1 - s1 * s1, s2 = 2.f * c1 * s1;
        float c3 = c1 * c2 - s1 * s2, s3 = c1 * s2 + s1 * c2;
        float z1r = y1r * c1 - y1i * s1, z1i = y1r * s1 + y1i * c1;
        float z2r = y2r * c2 - y2i * s2, z2i = y2r * s2 + y2i * c2;
        float z3r = y3r * c3 - y3i * s3, z3i = y3r * s3 + y3i * c3;
        float u0r = y0r + z2r, u0i = y0i + z2i;
        float u2r = y0r - z2r, u2i = y0i - z2i;
        float u1r = z1r + z3r, u1i = z1i + z3i;
        float u3r = z3i - z1i, u3i = z1r - z3r;
        RE[PD(i0)] = u0r + u1r; IM[PD(i0)] = u0i + u1i;
        RE[PD(i1)] = u2r + u3r; IM[PD(i1)] = u2i + u3i;
        RE[PD(i2)] = u0r - u1r; IM[PD(i2)] = u0i - u1i;
        RE[PD(i3)] = u2r - u3r; IM[PD(i3)] = u2i - u3i;
      }
      __syncthreads();
    }
    #pragma unroll
    for (int k = 0; k < 4; ++k) {
      int p = 4 * (tid + (k << 8));
      w[4 * k + 0] = RE[PD(p + 0)] * (1.0f / 4096.0f);
      w[4 * k + 1] = RE[PD(p + 1)] * (1.0f / 4096.0f);
      w[4 * k + 2] = RE[PD(p + 2)] * (1.0f / 4096.0f);
      w[4 * k + 3] = RE[PD(p + 3)] * (1.0f / 4096.0f);
    }
  } else {
    #pragma unroll
    for (int k = 0; k < 4; ++k) {
      w[4 * k + 0] = v4[k].x; w[4 * k + 1] = v4[k].y;
      w[4 * k + 2] = v4[k].z; w[4 * k + 3] = v4[k].w;
    }
  }
  if (at) {
    #pragma unroll
    for (int i = 0; i < 16; ++i) {
      int col = 4 * (tid + ((i >> 2) << 8)) + (i & 3);
      if (col >= t0 && col < t0 + 204) w[i] *= 0.1f;
    }
  }
  float4* d4 = reinterpret_cast<float4*>(dst + (size_t)row * T_LEN);
  #pragma unroll
  for (int k = 0; k < 4; ++k)
    d4[tid + (k << 8)] = make_float4(w[4 * k], w[4 * k + 1], w[4 * k + 2], w[4 * k + 3]);
}

// ---------------- role 2: additive noise on x -> o3 ----------------
__device__ void noise_row(float* smem, const float* __restrict__ src,
                          float* __restrict__ dst, int row,
                          uint32_t kx, uint32_t ky) {
  const int tid = threadIdx.x;
  const float4* s4 = reinterpret_cast<const float4*>(src + (size_t)row * T_LEN);
  float4 v4[4];
  #pragma unroll
  for (int k = 0; k < 4; ++k) v4[k] = s4[tid + (k << 8)];
  float nv[16];
  #pragma unroll
  for (int k = 0; k < 4; ++k) {
    nv[4 * k + 0] = v4[k].x; nv[4 * k + 1] = v4[k].y;
    nv[4 * k + 2] = v4[k].z; nv[4 * k + 3] = v4[k].w;
  }
  float* red = smem;
  float acc = 0.f;
  #pragma unroll
  for (int i = 0; i < 16; ++i) acc += nv[i];
  red[tid] = acc; __syncthreads();
  for (int o = 128; o > 0; o >>= 1) { if (tid < o) red[tid] += red[tid + o]; __syncthreads(); }
  float mu = red[0] * (1.0f / 4096.0f);
  __syncthreads();
  acc = 0.f;
  #pragma unroll
  for (int i = 0; i < 16; ++i) { float dv = nv[i] - mu; acc += dv * dv; }
  red[tid] = acc; __syncthreads();
  for (int o = 128; o > 0; o >>= 1) { if (tid < o) red[tid] += red[tid + o]; __syncthreads(); }
  float sigma = sqrtf(red[0] / 4095.0f);

  float4* n4 = reinterpret_cast<float4*>(dst + (size_t)row * T_LEN);
  #pragma unroll
  for (int k = 0; k < 4; ++k) {
    float o[4];
    #pragma unroll
    for (int c = 0; c < 4; ++c) {
      uint32_t col = (uint32_t)(4 * (tid + (k << 8)) + c);
      uint32_t idx = ((uint32_t)row << 12) + col;
      float z = jax_normal_from_bits(jbits_elem(kx, ky, idx));
      o[c] = nv[4 * k + c] + __fmul_rn(__fmul_rn(z, 0.02f), sigma);
    }
    n4[tid + (k << 8)] = make_float4(o[0], o[1], o[2], o[3]);
  }
}

// ---------------- merged kernel: 3 roles, fine-grained CU mixing ------------
__global__ __launch_bounds__(256)
void mega_kernel(const float* __restrict__ x,
                 float* __restrict__ o0, float* __restrict__ o1,
                 float* __restrict__ o2, float* __restrict__ o3,
                 float* __restrict__ o4,
                 int fuse, int at_c, int t0_c, uint32_t kcx, uint32_t kcy,
                 int afd, int f0d, int atd, int t0d, uint32_t knx, uint32_t kny) {
  extern __shared__ float smem[];
  int b = blockIdx.x;
  int role = (b >> 1) % 3;
  int row = ((b >> 1) / 3) * 2 + (b & 1);
  if (role == 0)
    wavelet_row(smem, x, o0, o1, o4, row, fuse, at_c, t0_c, kcx, kcy);
  else if (role == 1)
    fft_distort_row(smem, x, o2, row, afd, f0d, atd, t0d);
  else
    noise_row(smem, x, o3, row, knx, kny);
}

// ---------------- fallback kernel for afc==true (distort+noise on o4) -------
__global__ __launch_bounds__(256)
void distort_noise_kernel(const float* __restrict__ src, float* __restrict__ dst,
                          int af, int f0, int at, int t0, uint32_t kx, uint32_t ky) {
  extern __shared__ float smem[];
  const int row = blockIdx.x, tid = threadIdx.x;
  // distort into w via shared helper (writes dst after noise)
  // reuse fft_distort_row's logic inline: distort then noise over distorted.
  // For simplicity: distort to registers via fft path writing to dst first,
  // then reload is avoided by recomputing noise from w. We inline both here.
  // (This path only runs when afc==true.)
  float* RE = smem;
  float* IM = smem + 4224;
  float2* STW = (float2*)(smem + 8448);
  const float4* s4 = reinterpret_cast<const float4*>(src + (size_t)row * T_LEN);
  float4 v4[4];
  #pragma unroll
  for (int k = 0; k < 4; ++k) v4[k] = s4[tid + (k << 8)];
  float w[16];
  if (af) {
    for (int t = tid; t < 1365; t += 256) {
      int s, j;
      if (t < 1024) { s = 0; j = t; }
      else if (t < 1280) { s = 1; j = t - 1024; }
      else if (t < 1344) { s = 2; j = t - 1280; }
      else if (t < 1360) { s = 3; j = t - 1344; }
      else if (t < 1364) { s = 4; j = t - 1360; }
      else { s = 5; j = 0; }
      int e = j << (2 * s);
      float ang = (float)e * (-1.5339807878856412e-3f);
      float sn, cs;
      __sincosf(ang, &sn, &cs);
      STW[t] = make_float2(cs, sn);
    }
    #pragma unroll
    for (int k = 0; k < 4; ++k) {
      int p = 4 * (tid + (k << 8));
      RE[PD(p + 0)] = v4[k].x; IM[PD(p + 0)] = 0.f;
      RE[PD(p + 1)] = v4[k].y; IM[PD(p + 1)] = 0.f;
      RE[PD(p + 2)] = v4[k].z; IM[PD(p + 2)] = 0.f;
      RE[PD(p + 3)] = v4[k].w; IM[PD(p + 3)] = 0.f;
    }
    __syncthreads();
    for (int s = 0; s < 6; ++s) {
      int Lsh = 12 - 2 * s, Qsh = Lsh - 2, Qm = (1 << Qsh) - 1, off = c_STW_OFF[s];
      for (int b = tid; b < 1024; b += 256) {
        int j = b & Qm, g = b >> Qsh;
        int i0 = (g << Lsh) + j;
        int i1 = i0 + (1 << Qsh), i2 = i1 + (1 << Qsh), i3 = i2 + (1 << Qsh);
        float x0r = RE[PD(i0)], x0i = IM[PD(i0)];
        float x1r = RE[PD(i1)], x1i = IM[PD(i1)];
        float x2r = RE[PD(i2)], x2i = IM[PD(i2)];
        float x3r = RE[PD(i3)], x3i = IM[PD(i3)];
        float t0r = x0r + x2r, t0i = x0i + x2i;
        float t1r = x0r - x2r, t1i = x0i - x2i;
        float t2r = x1r + x3r, t2i = x1i + x3i;
        float t3r = x1r - x3r, t3i = x1i - x3i;
        float2 w1 = STW[off + j];
        float c1 = w1.x, s1 = w1.y;
        float c2 = c1 * c1 - s1 * s1, s2 = 2.f * c1 * s1;
        float c3 = c1 * c2 - s1 * s2, s3 = c1 * s2 + s1 * c2;
        RE[PD(i0)] = t0r + t2r; IM[PD(i0)] = t0i + t2i;
        float u1r = t1r + t3i, u1i = t1i - t3r;
        RE[PD(i1)] = u1r * c1 - u1i * s1; IM[PD(i1)] = u1r * s1 + u1i * c1;
        float u2r = t0r - t2r, u2i = t0i - t2i;
        RE[PD(i2)] = u2r * c2 - u2i * s2; IM[PD(i2)] = u2r * s2 + u2i * c2;
        float u3r = t1r - t3i, u3i = t1i + t3r;
        RE[PD(i3)] = u3r * c3 - u3i * s3; IM[PD(i3)] = u3r * s3 + u3i * c3;
      }
      __syncthreads();
    }
    for (int p = tid; p < 4096; p += 256) {
      uint32_t rb = __brev((uint32_t)p) >> 20;
      int kk = (int)(((rb & 0x555u) << 1) | ((rb >> 1) & 0x555u));
      if (kk >= f0 && kk < f0 + 409) { RE[PD(p)] *= 0.1f; IM[PD(p)] *= 0.1f; }
    }
    __syncthreads();
    for (int s = 5; s >= 0; --s) {
      int Lsh = 12 - 2 * s, Qsh = Lsh - 2, Qm = (1 << Qsh) - 1, off = c_STW_OFF[s];
      for (int b = tid; b < 1024; b += 256) {
        int j = b & Qm, g = b >> Qsh;
        int i0 = (g << Lsh) + j;
        int i1 = i0 + (1 << Qsh), i2 = i1 + (1 << Qsh), i3 = i2 + (1 << Qsh);
        float y0r = RE[PD(i0)], y0i = IM[PD(i0)];
        float y1r = RE[PD(i1)], y1i = IM[PD(i1)];
        float y2r = RE[PD(i2)], y2i = IM[PD(i2)];
        float y3r = RE[PD(i3)], y3i = IM[PD(i3)];
        float2 w1 = STW[off + j];
        float c1 = w1.x, s1 = -w1.y;
        float c2 = c1 * c1 - s1 * s1, s2 = 2.f * c1 * s1;
        float c3 = c1 * c2 - s1 * s2, s3 = c1 * s2 + s1 * c2;
        float z1r = y1r * c1 - y1i * s1, z1i = y1r * s1 + y1i * c1;
        float z2r = y2r * c2 - y2i * s2, z2i = y2r * s2 + y2i * c2;
        float z3r = y3r * c3 - y3i * s3, z3i = y3r * s3 + y3i * c3;
        float u0r = y0r + z2r, u0i = y0i + z2i;
        float u2r = y0r - z2r, u2i = y0i - z2i;
        float u1r = z1r + z3r, u1i = z1i + z3i;
        float u3r = z3i - z1i, u3i = z1r - z3r;
        RE[PD(i0)] = u0r + u1r; IM[PD(i0)] = u0i + u1i;
        RE[PD(i1)] = u2r + u3r; IM[PD(i1)] = u2i + u3i;
        RE[PD(i2)] = u0r - u1r; IM[PD(i2)] = u0i - u1i;
        RE[PD(i3)] = u2r - u3r; IM[PD(i3)] = u2i - u3i;
      }
      __syncthreads();
    }
    #pragma unroll
    for (int k = 0; k < 4; ++k) {
      int p = 4 * (tid + (k << 8));
      w[4 * k + 0] = RE[PD(p + 0)] * (1.0f / 4096.0f);
      w[4 * k + 1] = RE[PD(p + 1)] * (1.0f / 4096.0f);
      w[4 * k + 2] = RE[PD(p + 2)] * (1.0f / 4096.0f);
      w[4 * k + 3] = RE[PD(p + 3)] * (1.0f / 4096.0f);
    }
    __syncthreads();
  } else {
    #pragma unroll
    for (int k = 0; k < 4; ++k) {
      w[4 * k + 0] = v4[k].x; w[4 * k + 1] = v4[k].y;
      w[4 * k + 2] = v4[k].z; w[4 * k + 3] = v4[k].w;
    }
  }
  if (at) {
    #pragma unroll
    for (int i = 0; i < 16; ++i) {
      int col = 4 * (tid + ((i >> 2) << 8)) + (i & 3);
      if (col >= t0 && col < t0 + 204) w[i] *= 0.1f;
    }
  }
  float* red = smem;
  float acc = 0.f;
  #pragma unroll
  for (int i = 0; i < 16; ++i) acc += w[i];
  red[tid] = acc; __syncthreads();
  for (int o = 128; o > 0; o >>= 1) { if (tid < o) red[tid] += red[tid + o]; __syncthreads(); }
  float mu = red[0] * (1.0f / 4096.0f);
  __syncthreads();
  acc = 0.f;
  #pragma unroll
  for (int i = 0; i < 16; ++i) { float dv = w[i] - mu; acc += dv * dv; }
  red[tid] = acc; __syncthreads();
  for (int o = 128; o > 0; o >>= 1) { if (tid < o) red[tid] += red[tid + o]; __syncthreads(); }
  float sigma = sqrtf(red[0] / 4095.0f);
  float4* n4 = reinterpret_cast<float4*>(dst + (size_t)row * T_LEN);
  #pragma unroll
  for (int k = 0; k < 4; ++k) {
    float o[4];
    #pragma unroll
    for (int c = 0; c < 4; ++c) {
      uint32_t col = (uint32_t)(4 * (tid + (k << 8)) + c);
      uint32_t idx = ((uint32_t)row << 12) + col;
      float z = jax_normal_from_bits(jbits_elem(kx, ky, idx));
      o[c] = w[4 * k + c] + __fmul_rn(__fmul_rn(z, 0.02f), sigma);
    }
    n4[tid + (k << 8)] = make_float4(o[0], o[1], o[2], o[3]);
  }
}

// ---------------- launcher ----------------
extern "C" void kernel_launch(void* const* d_in, const int* in_sizes, int n_in,
                              void* d_out, int out_size, void* d_ws, size_t ws_size,
                              hipStream_t stream) {
  const float* x = (const float*)d_in[0];
  float* out = (float*)d_out;
  float* o0 = out;
  float* o1 = out + (size_t)N_ELEM;
  float* o2 = out + 2 * (size_t)N_ELEM;
  float* o3 = out + 3 * (size_t)N_ELEM;
  float* o4 = out + 4 * (size_t)N_ELEM;

  uint32_t r[8];
  jsplit4(0u, 42u, r);  // kd, kn, kcd, kcn
  int f0d, afd, t0d, atd, f0c, afc, t0c, atc;
  distort_params(r[0], r[1], &f0d, &afd, &t0d, &atd);
  distort_params(r[4], r[5], &f0c, &afc, &t0c, &atc);

  const size_t MEGA_LDS = 11178u * 4u;   // 44712 B -> 3 blocks/CU

  hipLaunchKernelGGL(mega_kernel, dim3(3 * N_ROWS), dim3(256), MEGA_LDS, stream,
                     x, o0, o1, o2, o3, o4,
                     afc ? 0 : 1, atc, t0c, r[6], r[7],
                     afd, f0d, atd, t0d, r[2], r[3]);
  if (afc) {
    hipLaunchKernelGGL(distort_noise_kernel, dim3(N_ROWS), dim3(256), MEGA_LDS, stream,
                       o4, o4, 1, f0c, atc, t0c, r[6], r[7]);
  }
}

// Round 10
// 329.134 us; speedup vs baseline: 1.0919x; 1.0919x over previous
//
#include <hip/hip_runtime.h>
#include <stdint.h>

#define T_LEN 4096
#define N_ROWS 4096
#define N_ELEM (4096u * 4096u)
#define PD(i) ((i) + ((i) >> 5))

// ---------------- wavelet filters (db4) ----------------
__constant__ float c_DEC_LO[8] = {
  -0.010597401785069032f, 0.0328830116668852f, 0.030841381835560764f,
  -0.18703481171909309f, -0.027983769416859854f, 0.6308807679298589f,
   0.7148465705529157f, 0.2303778133088965f };
__constant__ float c_DEC_HI[8] = {
  -0.2303778133088965f, 0.7148465705529157f, -0.6308807679298589f,
  -0.027983769416859854f, 0.18703481171909309f, 0.030841381835560764f,
  -0.0328830116668852f, -0.010597401785069032f };

#define RL0 0.2303778133088965f
#define RL1 0.7148465705529157f
#define RL2 0.6308807679298589f
#define RL3 (-0.027983769416859854f)
#define RL4 (-0.18703481171909309f)
#define RL5 0.030841381835560764f
#define RL6 0.0328830116668852f
#define RL7 (-0.010597401785069032f)
#define RH0 (-0.010597401785069032f)
#define RH1 (-0.0328830116668852f)
#define RH2 0.030841381835560764f
#define RH3 0.18703481171909309f
#define RH4 (-0.027983769416859854f)
#define RH5 (-0.6308807679298589f)
#define RH6 0.7148465705529157f
#define RH7 (-0.2303778133088965f)

// ---------------- Threefry-2x32 (host+device) ----------------
__host__ __device__ __forceinline__ uint32_t rotl32(uint32_t v, int r) {
  return (v << r) | (v >> (32 - r));
}

__host__ __device__ __forceinline__ void tf2x32(uint32_t k0, uint32_t k1,
                                                uint32_t c0, uint32_t c1,
                                                uint32_t& o0, uint32_t& o1) {
  uint32_t ks2 = k0 ^ k1 ^ 0x1BD11BDAu;
  uint32_t x0 = c0 + k0;
  uint32_t x1 = c1 + k1;
#define TFR(r) { x0 += x1; x1 = rotl32(x1, r); x1 ^= x0; }
  TFR(13) TFR(15) TFR(26) TFR(6)
  x0 += k1;  x1 += ks2 + 1u;
  TFR(17) TFR(29) TFR(16) TFR(24)
  x0 += ks2; x1 += k0 + 2u;
  TFR(13) TFR(15) TFR(26) TFR(6)
  x0 += k0;  x1 += k1 + 3u;
  TFR(17) TFR(29) TFR(16) TFR(24)
  x0 += k1;  x1 += ks2 + 4u;
  TFR(13) TFR(15) TFR(26) TFR(6)
  x0 += ks2; x1 += k0 + 5u;
#undef TFR
  o0 = x0; o1 = x1;
}

__host__ __device__ __forceinline__ uint32_t jbits_scalar(uint32_t kx, uint32_t ky) {
  uint32_t a, b; tf2x32(kx, ky, 0u, 0u, a, b);
  return a ^ b;
}

__device__ __forceinline__ uint32_t jbits_elem(uint32_t kx, uint32_t ky, uint32_t i) {
  uint32_t a, b; tf2x32(kx, ky, 0u, i, a, b); return a ^ b;
}

__host__ __device__ __forceinline__ float junif_scalar(uint32_t kx, uint32_t ky) {
  union { uint32_t u; float f; } cv;
  cv.u = (jbits_scalar(kx, ky) >> 9) | 0x3f800000u;
  return cv.f - 1.0f;
}

__host__ __device__ __forceinline__ void jsplit2(uint32_t kx, uint32_t ky, uint32_t* o) {
  tf2x32(kx, ky, 0u, 0u, o[0], o[1]);
  tf2x32(kx, ky, 0u, 1u, o[2], o[3]);
}

__host__ __device__ __forceinline__ void jsplit4(uint32_t kx, uint32_t ky, uint32_t* o) {
  tf2x32(kx, ky, 0u, 0u, o[0], o[1]);
  tf2x32(kx, ky, 0u, 1u, o[2], o[3]);
  tf2x32(kx, ky, 0u, 2u, o[4], o[5]);
  tf2x32(kx, ky, 0u, 3u, o[6], o[7]);
}

__host__ __device__ __forceinline__ int jrandint(uint32_t kx, uint32_t ky, uint32_t span) {
  uint32_t c[4];
  jsplit2(kx, ky, c);
  uint32_t hi = jbits_scalar(c[0], c[1]);
  uint32_t lo = jbits_scalar(c[2], c[3]);
  uint32_t mult = 65536u % span;
  mult = (mult * mult) % span;
  uint32_t off = ((hi % span) * mult + (lo % span)) % span;
  return (int)off;
}

__host__ __device__ void distort_params(uint32_t kx, uint32_t ky,
                                        int* f0, int* af, int* t0, int* at) {
  uint32_t q[8];
  jsplit4(kx, ky, q);
  *af = junif_scalar(q[0], q[1]) < 0.3f;
  *f0 = jrandint(q[2], q[3], 3687u);
  *at = junif_scalar(q[4], q[5]) < 0.3f;
  *t0 = jrandint(q[6], q[7], 3892u);
}

__device__ __forceinline__ float erfinv32(float x) {
  float w = -log1pf(-x * x);
  float p;
  if (w < 5.0f) {
    w = w - 2.5f;
    p = 2.81022636e-08f;
    p = fmaf(p, w, 3.43273939e-07f);
    p = fmaf(p, w, -3.5233877e-06f);
    p = fmaf(p, w, -4.39150654e-06f);
    p = fmaf(p, w, 0.00021858087f);
    p = fmaf(p, w, -0.00125372503f);
    p = fmaf(p, w, -0.00417768164f);
    p = fmaf(p, w, 0.246640727f);
    p = fmaf(p, w, 1.50140941f);
  } else {
    w = sqrtf(w) - 3.0f;
    p = -0.000200214257f;
    p = fmaf(p, w, 0.000100950558f);
    p = fmaf(p, w, 0.00134934322f);
    p = fmaf(p, w, -0.00367342844f);
    p = fmaf(p, w, 0.00573950773f);
    p = fmaf(p, w, -0.0076224613f);
    p = fmaf(p, w, 0.00943887047f);
    p = fmaf(p, w, 1.00167406f);
    p = fmaf(p, w, 2.83297682f);
  }
  return p * x;
}

__device__ __forceinline__ float jax_normal_from_bits(uint32_t bits) {
  union { uint32_t u; float f; } cv;
  cv.u = (bits >> 9) | 0x3f800000u;
  float f = cv.f - 1.0f;
  const float lo = -0.99999994f;
  float u = __fadd_rn(__fmul_rn(f, 2.0f), lo);
  u = fmaxf(lo, u);
  return 1.41421356f * erfinv32(u);
}

// numpy tree-of-8 sum
__device__ __forceinline__ float tree8(const float* p) {
  return __fadd_rn(
      __fadd_rn(__fadd_rn(p[0], p[1]), __fadd_rn(p[2], p[3])),
      __fadd_rn(__fadd_rn(p[4], p[5]), __fadd_rn(p[6], p[7])));
}

// ---------------- wavelet steps (per-output arithmetic bit-exact vs r6-r8) --
__device__ __forceinline__ void dwt_one(const float* a, int n, int i,
                                        float* oA, float* oD) {
  int base = 2 * i - 6;
  float pa[8], pd[8];
  #pragma unroll
  for (int j = 0; j < 8; ++j) {
    int q = base + j;
    q = (q < 0) ? (-q - 1) : ((q >= n) ? (2 * n - 1 - q) : q);
    float xv = a[q];
    pa[j] = __fmul_rn(c_DEC_LO[7 - j], xv);
    pd[j] = __fmul_rn(c_DEC_HI[7 - j], xv);
  }
  *oA = tree8(pa); *oD = tree8(pd);
}

__device__ void dwt_step(const float* a, int n, float* oa, float* od,
                         int nOut, int tid) {
  int iHi = (n - 2) >> 1;
  int nPair = nOut >> 1;
  for (int u = tid; u < nPair; u += 256) {
    int i0 = 2 * u;
    if (u >= 2 && (i0 + 1) <= iHi) {
      int base = 2 * i0 - 6;
      float x[10];
      #pragma unroll
      for (int j = 0; j < 10; ++j) x[j] = a[base + j];
      float p0[8], p1[8], q0[8], q1[8];
      #pragma unroll
      for (int j = 0; j < 8; ++j) {
        p0[j] = __fmul_rn(c_DEC_LO[7 - j], x[j]);
        q0[j] = __fmul_rn(c_DEC_HI[7 - j], x[j]);
        p1[j] = __fmul_rn(c_DEC_LO[7 - j], x[j + 2]);
        q1[j] = __fmul_rn(c_DEC_HI[7 - j], x[j + 2]);
      }
      *reinterpret_cast<float2*>(&oa[i0]) = make_float2(tree8(p0), tree8(p1));
      *reinterpret_cast<float2*>(&od[i0]) = make_float2(tree8(q0), tree8(q1));
    } else {
      float a0, d0, a1, d1;
      dwt_one(a, n, i0, &a0, &d0);
      dwt_one(a, n, i0 + 1, &a1, &d1);
      oa[i0] = a0; od[i0] = d0;
      oa[i0 + 1] = a1; od[i0 + 1] = d1;
    }
  }
  for (int i = 2 * nPair + tid; i < nOut; i += 256) {
    float av, dv;
    dwt_one(a, n, i, &av, &dv);
    oa[i] = av; od[i] = dv;
  }
}

// pair idwt: outputs t=2h and t=2h+1 share all 8 loads + thresholds.
__device__ __forceinline__ void idwt_pair_vals(const float* __restrict__ a,
                                               const float* __restrict__ d,
                                               int h, float thr, bool trA,
                                               float* ev, float* ov) {
  float a0 = a[h], a1 = a[h + 1], a2 = a[h + 2], a3 = a[h + 3];
  if (trA) {
    a0 = (fabsf(a0) < thr) ? 0.f : a0;
    a1 = (fabsf(a1) < thr) ? 0.f : a1;
    a2 = (fabsf(a2) < thr) ? 0.f : a2;
    a3 = (fabsf(a3) < thr) ? 0.f : a3;
  }
  float d0 = d[h], d1 = d[h + 1], d2 = d[h + 2], d3 = d[h + 3];
  d0 = (fabsf(d0) < thr) ? 0.f : d0;
  d1 = (fabsf(d1) < thr) ? 0.f : d1;
  d2 = (fabsf(d2) < thr) ? 0.f : d2;
  d3 = (fabsf(d3) < thr) ? 0.f : d3;
  float saE = __fadd_rn(__fadd_rn(__fmul_rn(RL6, a0), __fmul_rn(RL4, a1)),
                        __fadd_rn(__fmul_rn(RL2, a2), __fmul_rn(RL0, a3)));
  float sdE = __fadd_rn(__fadd_rn(__fmul_rn(RH6, d0), __fmul_rn(RH4, d1)),
                        __fadd_rn(__fmul_rn(RH2, d2), __fmul_rn(RH0, d3)));
  float saO = __fadd_rn(__fadd_rn(__fmul_rn(RL7, a0), __fmul_rn(RL5, a1)),
                        __fadd_rn(__fmul_rn(RL3, a2), __fmul_rn(RL1, a3)));
  float sdO = __fadd_rn(__fadd_rn(__fmul_rn(RH7, d0), __fmul_rn(RH5, d1)),
                        __fadd_rn(__fmul_rn(RH3, d2), __fmul_rn(RH1, d3)));
  *ev = __fadd_rn(saE, sdE);
  *ov = __fadd_rn(saO, sdO);
}

__device__ void idwt_step(const float* __restrict__ a, const float* __restrict__ d,
                          float* __restrict__ out, int nOut, float thr,
                          bool trA, int tid) {
  int nPair = nOut >> 1;
  for (int h = tid; h < nPair; h += 256) {
    float ev, ov;
    idwt_pair_vals(a, d, h, thr, trA, &ev, &ov);
    *reinterpret_cast<float2*>(&out[2 * h]) = make_float2(ev, ov);
  }
  if (nOut & 1) {
    int h = nPair;  // last even output t = 2*nPair
    if (tid == (h & 255)) {
      float ev, ov;
      idwt_pair_vals(a, d, h, thr, trA, &ev, &ov);
      out[2 * h] = ev;
    }
  }
}

// last level: write float2 straight to global (4096 outputs, 8 pairs/thread)
__device__ void idwt_last_store(const float* __restrict__ a, const float* __restrict__ d,
                                float thr, int tid, float* __restrict__ dstRow) {
  #pragma unroll
  for (int k = 0; k < 8; ++k) {
    int h = tid + (k << 8);
    float ev, ov;
    idwt_pair_vals(a, d, h, thr, false, &ev, &ov);
    *reinterpret_cast<float2*>(&dstRow[2 * h]) = make_float2(ev, ov);
  }
}

__device__ void idwt_last_reg(const float* __restrict__ a, const float* __restrict__ d,
                              float thr, int tid, float* w) {
  #pragma unroll
  for (int k = 0; k < 8; ++k) {
    int h = tid + (k << 8);
    idwt_pair_vals(a, d, h, thr, false, &w[2 * k], &w[2 * k + 1]);
  }
}

__device__ void np_pw262_partials(const float* src, float* pbuf, int tid) {
  if (tid < 24) {
    int blk = tid >> 3, k = tid & 7;
    const float* base = src + (blk == 0 ? 0 : (blk == 1 ? 128 : 192));
    int iters = (blk == 0 ? 16 : 8);
    float r = base[k];
    for (int it = 1; it < iters; ++it) r = __fadd_rn(r, base[8 * it + k]);
    pbuf[tid] = r;
  }
}

__device__ float np_pw262_combine(const float* src, const float* pbuf) {
  float b0 = tree8(pbuf + 0);
  float b1 = tree8(pbuf + 8);
  float b2 = tree8(pbuf + 16);
  for (int i = 256; i < 262; ++i) b2 = __fadd_rn(b2, src[i]);
  return __fadd_rn(b0, __fadd_rn(b1, b2));
}

// ---------------- wavelet kernel (o0, o1, o4[; fused mask+noise]) ----------
__global__ __launch_bounds__(256)
void wavelet_kernel(const float* __restrict__ x, float* __restrict__ out0,
                    float* __restrict__ out1, float* __restrict__ out4,
                    int fuse, int at_c, int t0_c, uint32_t kcx, uint32_t kcy) {
  extern __shared__ float smem[];
  float* A  = smem;              // 4096
  float* B  = smem + 4096;       // 2052 (even base)
  float* D1 = smem + 6148;       // 2052
  float* D2 = smem + 8200;       // 1030
  float* D3 = smem + 9230;       // 518
  float* D4 = smem + 9748;       // 262
  float* SC = smem + 10010;      // 2
  float* Bp = B + 512;           // 24 partials scratch (B free at that point)
  const int row = blockIdx.x, tid = threadIdx.x;
  const float4* s4 = reinterpret_cast<const float4*>(x + (size_t)row * T_LEN);
  float4* o04 = reinterpret_cast<float4*>(out0 + (size_t)row * T_LEN);
  #pragma unroll
  for (int k = 0; k < 4; ++k) {
    float4 v = s4[tid + (k << 8)];
    *reinterpret_cast<float4*>(&A[4 * (tid + (k << 8))]) = v;
    o04[tid + (k << 8)] = v;
  }
  __syncthreads();
  dwt_step(A, 4096, B, D1, 2051, tid); __syncthreads();
  dwt_step(B, 2051, A, D2, 1029, tid); __syncthreads();
  dwt_step(A, 1029, B, D3, 518, tid);  __syncthreads();
  dwt_step(B, 518, A, D4, 262, tid);   __syncthreads();  // a4 -> A[0:262)

  // sigma(a4), ddof=0, exact numpy pairwise order
  np_pw262_partials(A, Bp, tid);
  __syncthreads();
  if (tid == 0) SC[0] = np_pw262_combine(A, Bp) / 262.0f;
  __syncthreads();
  float mu = SC[0];
  for (int i = tid; i < 262; i += 256) {
    float dv = __fsub_rn(A[i], mu);
    B[i] = __fmul_rn(dv, dv);
  }
  __syncthreads();
  np_pw262_partials(B, Bp, tid);
  __syncthreads();
  if (tid == 0) SC[1] = __fsqrt_rn(np_pw262_combine(B, Bp) / 262.0f);
  __syncthreads();
  float sigma = SC[1];

  // stash a4 (A gets clobbered by idwt chain)
  float ra0 = A[tid];
  float ra1 = (tid < 6) ? A[256 + tid] : 0.f;

  // ---- v = 0 : thr = 0.5*sigma -> out1 ----
  {
    float thr = __fmul_rn(0.5f, sigma);
    idwt_step(A, D4, B, 518, thr, true, tid);   __syncthreads();
    idwt_step(B, D3, A, 1029, thr, false, tid); __syncthreads();
    idwt_step(A, D2, B, 2051, thr, false, tid); __syncthreads();
    idwt_last_store(B, D1, thr, tid, out1 + (size_t)row * T_LEN);
    __syncthreads();
  }
  // restore a4
  A[tid] = ra0;
  if (tid < 6) A[256 + tid] = ra1;
  __syncthreads();

  // ---- v = 1 : thr = 0.25*sigma -> out4 ----
  float thr = __fmul_rn(0.25f, sigma);
  idwt_step(A, D4, B, 518, thr, true, tid);   __syncthreads();
  idwt_step(B, D3, A, 1029, thr, false, tid); __syncthreads();
  idwt_step(A, D2, B, 2051, thr, false, tid); __syncthreads();

  float* dstRow = out4 + (size_t)row * T_LEN;
  if (!fuse) {
    idwt_last_store(B, D1, thr, tid, dstRow);
    return;
  }

  // fused (af_c == false): reconstruct to registers, time-mask, noise, store
  float w[16];
  idwt_last_reg(B, D1, thr, tid, w);
  if (at_c) {
    #pragma unroll
    for (int k = 0; k < 8; ++k) {
      #pragma unroll
      for (int c = 0; c < 2; ++c) {
        int col = 2 * (tid + (k << 8)) + c;
        if (col >= t0_c && col < t0_c + 204) w[2 * k + c] *= 0.1f;
      }
    }
  }
  __syncthreads();
  float* red = B;
  float acc = 0.f;
  #pragma unroll
  for (int i = 0; i < 16; ++i) acc += w[i];
  red[tid] = acc; __syncthreads();
  for (int o = 128; o > 0; o >>= 1) { if (tid < o) red[tid] += red[tid + o]; __syncthreads(); }
  float nmu = red[0] * (1.0f / 4096.0f);
  __syncthreads();
  acc = 0.f;
  #pragma unroll
  for (int i = 0; i < 16; ++i) { float dv = w[i] - nmu; acc += dv * dv; }
  red[tid] = acc; __syncthreads();
  for (int o = 128; o > 0; o >>= 1) { if (tid < o) red[tid] += red[tid + o]; __syncthreads(); }
  float nsig = sqrtf(red[0] / 4095.0f);

  #pragma unroll
  for (int k = 0; k < 8; ++k) {
    int h = tid + (k << 8);
    float o2v[2];
    #pragma unroll
    for (int c = 0; c < 2; ++c) {
      uint32_t col = (uint32_t)(2 * h + c);
      uint32_t idx = ((uint32_t)row << 12) + col;
      float z = jax_normal_from_bits(jbits_elem(kcx, kcy, idx));
      o2v[c] = w[2 * k + c] + __fmul_rn(__fmul_rn(z, 0.02f), nsig);
    }
    *reinterpret_cast<float2*>(&dstRow[2 * h]) = make_float2(o2v[0], o2v[1]);
  }
}

// ---------------- radix-4 FFT distort + noise (r8, unchanged) ---------------
__constant__ int c_STW_OFF[6] = {0, 1024, 1280, 1344, 1360, 1364};

__global__ __launch_bounds__(256)
void distort_noise_kernel(const float* __restrict__ src, float* __restrict__ dst_d,
                          float* __restrict__ dst_n,
                          int af, int f0, int at, int t0, int nod, int wd,
                          uint32_t kx, uint32_t ky) {
  extern __shared__ float smem[];
  float* RE = smem;
  float* IM = smem + 4224;
  float2* STW = (float2*)(smem + 8448);
  const int row = blockIdx.x, tid = threadIdx.x;

  const float4* s4 = reinterpret_cast<const float4*>(src + (size_t)row * T_LEN);
  float4 v4[4];
  #pragma unroll
  for (int k = 0; k < 4; ++k) v4[k] = s4[tid + (k << 8)];

  float w[16];
  if (af) {
    for (int t = tid; t < 1365; t += 256) {
      int s, j;
      if (t < 1024) { s = 0; j = t; }
      else if (t < 1280) { s = 1; j = t - 1024; }
      else if (t < 1344) { s = 2; j = t - 1280; }
      else if (t < 1360) { s = 3; j = t - 1344; }
      else if (t < 1364) { s = 4; j = t - 1360; }
      else { s = 5; j = 0; }
      int e = j << (2 * s);
      float ang = (float)e * (-1.5339807878856412e-3f);
      float sn, cs;
      __sincosf(ang, &sn, &cs);
      STW[t] = make_float2(cs, sn);
    }
    #pragma unroll
    for (int k = 0; k < 4; ++k) {
      int p = 4 * (tid + (k << 8));
      RE[PD(p + 0)] = v4[k].x; IM[PD(p + 0)] = 0.f;
      RE[PD(p + 1)] = v4[k].y; IM[PD(p + 1)] = 0.f;
      RE[PD(p + 2)] = v4[k].z; IM[PD(p + 2)] = 0.f;
      RE[PD(p + 3)] = v4[k].w; IM[PD(p + 3)] = 0.f;
    }
    __syncthreads();
    for (int s = 0; s < 6; ++s) {
      int Lsh = 12 - 2 * s, Qsh = Lsh - 2, Qm = (1 << Qsh) - 1, off = c_STW_OFF[s];
      for (int b = tid; b < 1024; b += 256) {
        int j = b & Qm, g = b >> Qsh;
        int i0 = (g << Lsh) + j;
        int i1 = i0 + (1 << Qsh), i2 = i1 + (1 << Qsh), i3 = i2 + (1 << Qsh);
        float x0r = RE[PD(i0)], x0i = IM[PD(i0)];
        float x1r = RE[PD(i1)], x1i = IM[PD(i1)];
        float x2r = RE[PD(i2)], x2i = IM[PD(i2)];
        float x3r = RE[PD(i3)], x3i = IM[PD(i3)];
        float t0r = x0r + x2r, t0i = x0i + x2i;
        float t1r = x0r - x2r, t1i = x0i - x2i;
        float t2r = x1r + x3r, t2i = x1i + x3i;
        float t3r = x1r - x3r, t3i = x1i - x3i;
        float2 w1 = STW[off + j];
        float c1 = w1.x, s1 = w1.y;
        float c2 = c1 * c1 - s1 * s1, s2 = 2.f * c1 * s1;
        float c3 = c1 * c2 - s1 * s2, s3 = c1 * s2 + s1 * c2;
        RE[PD(i0)] = t0r + t2r; IM[PD(i0)] = t0i + t2i;
        float u1r = t1r + t3i, u1i = t1i - t3r;
        RE[PD(i1)] = u1r * c1 - u1i * s1; IM[PD(i1)] = u1r * s1 + u1i * c1;
        float u2r = t0r - t2r, u2i = t0i - t2i;
        RE[PD(i2)] = u2r * c2 - u2i * s2; IM[PD(i2)] = u2r * s2 + u2i * c2;
        float u3r = t1r - t3i, u3i = t1i + t3r;
        RE[PD(i3)] = u3r * c3 - u3i * s3; IM[PD(i3)] = u3r * s3 + u3i * c3;
      }
      __syncthreads();
    }
    for (int p = tid; p < 4096; p += 256) {
      uint32_t rb = __brev((uint32_t)p) >> 20;
      int kk = (int)(((rb & 0x555u) << 1) | ((rb >> 1) & 0x555u));
      if (kk >= f0 && kk < f0 + 409) { RE[PD(p)] *= 0.1f; IM[PD(p)] *= 0.1f; }
    }
    __syncthreads();
    for (int s = 5; s >= 0; --s) {
      int Lsh = 12 - 2 * s, Qsh = Lsh - 2, Qm = (1 << Qsh) - 1, off = c_STW_OFF[s];
      for (int b = tid; b < 1024; b += 256) {
        int j = b & Qm, g = b >> Qsh;
        int i0 = (g << Lsh) + j;
        int i1 = i0 + (1 << Qsh), i2 = i1 + (1 << Qsh), i3 = i2 + (1 << Qsh);
        float y0r = RE[PD(i0)], y0i = IM[PD(i0)];
        float y1r = RE[PD(i1)], y1i = IM[PD(i1)];
        float y2r = RE[PD(i2)], y2i = IM[PD(i2)];
        float y3r = RE[PD(i3)], y3i = IM[PD(i3)];
        float2 w1 = STW[off + j];
        float c1 = w1.x, s1 = -w1.y;
        float c2 = c1 * c1 - s1 * s1, s2 = 2.f * c1 * s1;
        float c3 = c1 * c2 - s1 * s2, s3 = c1 * s2 + s1 * c2;
        float z1r = y1r * c1 - y1i * s1, z1i = y1r * s1 + y1i * c1;
        float z2r = y2r * c2 - y2i * s2, z2i = y2r * s2 + y2i * c2;
        float z3r = y3r * c3 - y3i * s3, z3i = y3r * s3 + y3i * c3;
        float u0r = y0r + z2r, u0i = y0i + z2i;
        float u2r = y0r - z2r, u2i = y0i - z2i;
        float u1r = z1r + z3r, u1i = z1i + z3i;
        float u3r = z3i - z1i, u3i = z1r - z3r;
        RE[PD(i0)] = u0r + u1r; IM[PD(i0)] = u0i + u1i;
        RE[PD(i1)] = u2r + u3r; IM[PD(i1)] = u2i + u3i;
        RE[PD(i2)] = u0r - u1r; IM[PD(i2)] = u0i - u1i;
        RE[PD(i3)] = u2r - u3r; IM[PD(i3)] = u2i - u3i;
      }
      __syncthreads();
    }
    #pragma unroll
    for (int k = 0; k < 4; ++k) {
      int p = 4 * (tid + (k << 8));
      w[4 * k + 0] = RE[PD(p + 0)] * (1.0f / 4096.0f);
      w[4 * k + 1] = RE[PD(p + 1)] * (1.0f / 4096.0f);
      w[4 * k + 2] = RE[PD(p + 2)] * (1.0f / 4096.0f);
      w[4 * k + 3] = RE[PD(p + 3)] * (1.0f / 4096.0f);
    }
    __syncthreads();
  } else {
    #pragma unroll
    for (int k = 0; k < 4; ++k) {
      w[4 * k + 0] = v4[k].x; w[4 * k + 1] = v4[k].y;
      w[4 * k + 2] = v4[k].z; w[4 * k + 3] = v4[k].w;
    }
  }
  if (at) {
    #pragma unroll
    for (int i = 0; i < 16; ++i) {
      int col = 4 * (tid + ((i >> 2) << 8)) + (i & 3);
      if (col >= t0 && col < t0 + 204) w[i] *= 0.1f;
    }
  }
  if (wd) {
    float4* d4 = reinterpret_cast<float4*>(dst_d + (size_t)row * T_LEN);
    #pragma unroll
    for (int k = 0; k < 4; ++k)
      d4[tid + (k << 8)] = make_float4(w[4 * k], w[4 * k + 1], w[4 * k + 2], w[4 * k + 3]);
  }

  float nv[16];
  #pragma unroll
  for (int i = 0; i < 16; ++i) {
    float q;
    if (nod) q = w[i];
    else {
      float4 vv = v4[i >> 2];
      q = (i & 3) == 0 ? vv.x : (i & 3) == 1 ? vv.y : (i & 3) == 2 ? vv.z : vv.w;
    }
    nv[i] = q;
  }
  float* red = smem;
  float acc = 0.f;
  #pragma unroll
  for (int i = 0; i < 16; ++i) acc += nv[i];
  red[tid] = acc; __syncthreads();
  for (int o = 128; o > 0; o >>= 1) { if (tid < o) red[tid] += red[tid + o]; __syncthreads(); }
  float mu = red[0] * (1.0f / 4096.0f);
  __syncthreads();
  acc = 0.f;
  #pragma unroll
  for (int i = 0; i < 16; ++i) { float dv = nv[i] - mu; acc += dv * dv; }
  red[tid] = acc; __syncthreads();
  for (int o = 128; o > 0; o >>= 1) { if (tid < o) red[tid] += red[tid + o]; __syncthreads(); }
  float sigma = sqrtf(red[0] / 4095.0f);

  float4* n4 = reinterpret_cast<float4*>(dst_n + (size_t)row * T_LEN);
  #pragma unroll
  for (int k = 0; k < 4; ++k) {
    float o[4];
    #pragma unroll
    for (int c = 0; c < 4; ++c) {
      uint32_t col = (uint32_t)(4 * (tid + (k << 8)) + c);
      uint32_t idx = ((uint32_t)row << 12) + col;
      float z = jax_normal_from_bits(jbits_elem(kx, ky, idx));
      o[c] = nv[4 * k + c] + __fmul_rn(__fmul_rn(z, 0.02f), sigma);
    }
    n4[tid + (k << 8)] = make_float4(o[0], o[1], o[2], o[3]);
  }
}

// ---------------- launcher ----------------
extern "C" void kernel_launch(void* const* d_in, const int* in_sizes, int n_in,
                              void* d_out, int out_size, void* d_ws, size_t ws_size,
                              hipStream_t stream) {
  const float* x = (const float*)d_in[0];
  float* out = (float*)d_out;
  float* o0 = out;
  float* o1 = out + (size_t)N_ELEM;
  float* o2 = out + 2 * (size_t)N_ELEM;
  float* o3 = out + 3 * (size_t)N_ELEM;
  float* o4 = out + 4 * (size_t)N_ELEM;

  uint32_t r[8];
  jsplit4(0u, 42u, r);  // kd, kn, kcd, kcn
  int f0d, afd, t0d, atd, f0c, afc, t0c, atc;
  distort_params(r[0], r[1], &f0d, &afd, &t0d, &atd);
  distort_params(r[4], r[5], &f0c, &afc, &t0c, &atc);

  const size_t WAVE_LDS = 10012u * 4u;   // 40048 B -> 4 blocks/CU
  const size_t FFT_LDS  = 11178u * 4u;   // 44712 B -> 3 blocks/CU

  hipLaunchKernelGGL(wavelet_kernel, dim3(N_ROWS), dim3(256), WAVE_LDS, stream,
                     x, o0, o1, o4, afc ? 0 : 1, atc, t0c, r[6], r[7]);
  hipLaunchKernelGGL(distort_noise_kernel, dim3(N_ROWS), dim3(256),
                     afd ? FFT_LDS : 1024, stream,
                     x, o2, o3, afd, f0d, atd, t0d, 0, 1, r[2], r[3]);
  if (afc) {
    hipLaunchKernelGGL(distort_noise_kernel, dim3(N_ROWS), dim3(256), FFT_LDS, stream,
                       o4, o4, o4, 1, f0c, atc, t0c, 1, 0, r[6], r[7]);
  }
}

// Round 11
// 279.902 us; speedup vs baseline: 1.2840x; 1.1759x over previous
//
#include <hip/hip_runtime.h>
#include <stdint.h>

#define T_LEN 4096
#define N_ROWS 4096
#define N_ELEM (4096u * 4096u)
#define PD(i) ((i) + ((i) >> 5))

// ---------------- wavelet filters (db4) ----------------
__constant__ float c_DEC_LO[8] = {
  -0.010597401785069032f, 0.0328830116668852f, 0.030841381835560764f,
  -0.18703481171909309f, -0.027983769416859854f, 0.6308807679298589f,
   0.7148465705529157f, 0.2303778133088965f };
__constant__ float c_DEC_HI[8] = {
  -0.2303778133088965f, 0.7148465705529157f, -0.6308807679298589f,
  -0.027983769416859854f, 0.18703481171909309f, 0.030841381835560764f,
  -0.0328830116668852f, -0.010597401785069032f };

#define RL0 0.2303778133088965f
#define RL1 0.7148465705529157f
#define RL2 0.6308807679298589f
#define RL3 (-0.027983769416859854f)
#define RL4 (-0.18703481171909309f)
#define RL5 0.030841381835560764f
#define RL6 0.0328830116668852f
#define RL7 (-0.010597401785069032f)
#define RH0 (-0.010597401785069032f)
#define RH1 (-0.0328830116668852f)
#define RH2 0.030841381835560764f
#define RH3 0.18703481171909309f
#define RH4 (-0.027983769416859854f)
#define RH5 (-0.6308807679298589f)
#define RH6 0.7148465705529157f
#define RH7 (-0.2303778133088965f)

// ---------------- Threefry-2x32 (host+device) ----------------
__host__ __device__ __forceinline__ uint32_t rotl32(uint32_t v, int r) {
  return (v << r) | (v >> (32 - r));
}

__host__ __device__ __forceinline__ void tf2x32(uint32_t k0, uint32_t k1,
                                                uint32_t c0, uint32_t c1,
                                                uint32_t& o0, uint32_t& o1) {
  uint32_t ks2 = k0 ^ k1 ^ 0x1BD11BDAu;
  uint32_t x0 = c0 + k0;
  uint32_t x1 = c1 + k1;
#define TFR(r) { x0 += x1; x1 = rotl32(x1, r); x1 ^= x0; }
  TFR(13) TFR(15) TFR(26) TFR(6)
  x0 += k1;  x1 += ks2 + 1u;
  TFR(17) TFR(29) TFR(16) TFR(24)
  x0 += ks2; x1 += k0 + 2u;
  TFR(13) TFR(15) TFR(26) TFR(6)
  x0 += k0;  x1 += k1 + 3u;
  TFR(17) TFR(29) TFR(16) TFR(24)
  x0 += k1;  x1 += ks2 + 4u;
  TFR(13) TFR(15) TFR(26) TFR(6)
  x0 += ks2; x1 += k0 + 5u;
#undef TFR
  o0 = x0; o1 = x1;
}

__host__ __device__ __forceinline__ uint32_t jbits_scalar(uint32_t kx, uint32_t ky) {
  uint32_t a, b; tf2x32(kx, ky, 0u, 0u, a, b);
  return a ^ b;
}

__device__ __forceinline__ uint32_t jbits_elem(uint32_t kx, uint32_t ky, uint32_t i) {
  uint32_t a, b; tf2x32(kx, ky, 0u, i, a, b); return a ^ b;
}

__host__ __device__ __forceinline__ float junif_scalar(uint32_t kx, uint32_t ky) {
  union { uint32_t u; float f; } cv;
  cv.u = (jbits_scalar(kx, ky) >> 9) | 0x3f800000u;
  return cv.f - 1.0f;
}

__host__ __device__ __forceinline__ void jsplit2(uint32_t kx, uint32_t ky, uint32_t* o) {
  tf2x32(kx, ky, 0u, 0u, o[0], o[1]);
  tf2x32(kx, ky, 0u, 1u, o[2], o[3]);
}

__host__ __device__ __forceinline__ void jsplit4(uint32_t kx, uint32_t ky, uint32_t* o) {
  tf2x32(kx, ky, 0u, 0u, o[0], o[1]);
  tf2x32(kx, ky, 0u, 1u, o[2], o[3]);
  tf2x32(kx, ky, 0u, 2u, o[4], o[5]);
  tf2x32(kx, ky, 0u, 3u, o[6], o[7]);
}

__host__ __device__ __forceinline__ int jrandint(uint32_t kx, uint32_t ky, uint32_t span) {
  uint32_t c[4];
  jsplit2(kx, ky, c);
  uint32_t hi = jbits_scalar(c[0], c[1]);
  uint32_t lo = jbits_scalar(c[2], c[3]);
  uint32_t mult = 65536u % span;
  mult = (mult * mult) % span;
  uint32_t off = ((hi % span) * mult + (lo % span)) % span;
  return (int)off;
}

__host__ __device__ void distort_params(uint32_t kx, uint32_t ky,
                                        int* f0, int* af, int* t0, int* at) {
  uint32_t q[8];
  jsplit4(kx, ky, q);
  *af = junif_scalar(q[0], q[1]) < 0.3f;
  *f0 = jrandint(q[2], q[3], 3687u);
  *at = junif_scalar(q[4], q[5]) < 0.3f;
  *t0 = jrandint(q[6], q[7], 3892u);
}

__device__ __forceinline__ float erfinv32(float x) {
  float w = -log1pf(-x * x);
  float p;
  if (w < 5.0f) {
    w = w - 2.5f;
    p = 2.81022636e-08f;
    p = fmaf(p, w, 3.43273939e-07f);
    p = fmaf(p, w, -3.5233877e-06f);
    p = fmaf(p, w, -4.39150654e-06f);
    p = fmaf(p, w, 0.00021858087f);
    p = fmaf(p, w, -0.00125372503f);
    p = fmaf(p, w, -0.00417768164f);
    p = fmaf(p, w, 0.246640727f);
    p = fmaf(p, w, 1.50140941f);
  } else {
    w = sqrtf(w) - 3.0f;
    p = -0.000200214257f;
    p = fmaf(p, w, 0.000100950558f);
    p = fmaf(p, w, 0.00134934322f);
    p = fmaf(p, w, -0.00367342844f);
    p = fmaf(p, w, 0.00573950773f);
    p = fmaf(p, w, -0.0076224613f);
    p = fmaf(p, w, 0.00943887047f);
    p = fmaf(p, w, 1.00167406f);
    p = fmaf(p, w, 2.83297682f);
  }
  return p * x;
}

__device__ __forceinline__ float jax_normal_from_bits(uint32_t bits) {
  union { uint32_t u; float f; } cv;
  cv.u = (bits >> 9) | 0x3f800000u;
  float f = cv.f - 1.0f;
  const float lo = -0.99999994f;
  float u = __fadd_rn(__fmul_rn(f, 2.0f), lo);
  u = fmaxf(lo, u);
  return 1.41421356f * erfinv32(u);
}

// numpy tree-of-8 sum
__device__ __forceinline__ float tree8(const float* p) {
  return __fadd_rn(
      __fadd_rn(__fadd_rn(p[0], p[1]), __fadd_rn(p[2], p[3])),
      __fadd_rn(__fadd_rn(p[4], p[5]), __fadd_rn(p[6], p[7])));
}

// ---------------- wavelet steps (per-output arithmetic bit-exact vs r6-r10) -
__device__ __forceinline__ void dwt_one(const float* a, int n, int i,
                                        float* oA, float* oD) {
  int base = 2 * i - 6;
  float pa[8], pd[8];
  #pragma unroll
  for (int j = 0; j < 8; ++j) {
    int q = base + j;
    q = (q < 0) ? (-q - 1) : ((q >= n) ? (2 * n - 1 - q) : q);
    float xv = a[q];
    pa[j] = __fmul_rn(c_DEC_LO[7 - j], xv);
    pd[j] = __fmul_rn(c_DEC_HI[7 - j], xv);
  }
  *oA = tree8(pa); *oD = tree8(pd);
}

__device__ void dwt_step(const float* a, int n, float* oa, float* od,
                         int nOut, int tid) {
  int iHi = (n - 2) >> 1;
  int nPair = nOut >> 1;
  for (int u = tid; u < nPair; u += 256) {
    int i0 = 2 * u;
    if (u >= 2 && (i0 + 1) <= iHi) {
      int base = 2 * i0 - 6;
      float x[10];
      #pragma unroll
      for (int j = 0; j < 10; ++j) x[j] = a[base + j];
      float p0[8], p1[8], q0[8], q1[8];
      #pragma unroll
      for (int j = 0; j < 8; ++j) {
        p0[j] = __fmul_rn(c_DEC_LO[7 - j], x[j]);
        q0[j] = __fmul_rn(c_DEC_HI[7 - j], x[j]);
        p1[j] = __fmul_rn(c_DEC_LO[7 - j], x[j + 2]);
        q1[j] = __fmul_rn(c_DEC_HI[7 - j], x[j + 2]);
      }
      *reinterpret_cast<float2*>(&oa[i0]) = make_float2(tree8(p0), tree8(p1));
      *reinterpret_cast<float2*>(&od[i0]) = make_float2(tree8(q0), tree8(q1));
    } else {
      float a0, d0, a1, d1;
      dwt_one(a, n, i0, &a0, &d0);
      dwt_one(a, n, i0 + 1, &a1, &d1);
      oa[i0] = a0; od[i0] = d0;
      oa[i0 + 1] = a1; od[i0 + 1] = d1;
    }
  }
  for (int i = 2 * nPair + tid; i < nOut; i += 256) {
    float av, dv;
    dwt_one(a, n, i, &av, &dv);
    oa[i] = av; od[i] = dv;
  }
}

__device__ __forceinline__ void idwt_pair_vals(const float* __restrict__ a,
                                               const float* __restrict__ d,
                                               int h, float thr, bool trA,
                                               float* ev, float* ov) {
  float a0 = a[h], a1 = a[h + 1], a2 = a[h + 2], a3 = a[h + 3];
  if (trA) {
    a0 = (fabsf(a0) < thr) ? 0.f : a0;
    a1 = (fabsf(a1) < thr) ? 0.f : a1;
    a2 = (fabsf(a2) < thr) ? 0.f : a2;
    a3 = (fabsf(a3) < thr) ? 0.f : a3;
  }
  float d0 = d[h], d1 = d[h + 1], d2 = d[h + 2], d3 = d[h + 3];
  d0 = (fabsf(d0) < thr) ? 0.f : d0;
  d1 = (fabsf(d1) < thr) ? 0.f : d1;
  d2 = (fabsf(d2) < thr) ? 0.f : d2;
  d3 = (fabsf(d3) < thr) ? 0.f : d3;
  float saE = __fadd_rn(__fadd_rn(__fmul_rn(RL6, a0), __fmul_rn(RL4, a1)),
                        __fadd_rn(__fmul_rn(RL2, a2), __fmul_rn(RL0, a3)));
  float sdE = __fadd_rn(__fadd_rn(__fmul_rn(RH6, d0), __fmul_rn(RH4, d1)),
                        __fadd_rn(__fmul_rn(RH2, d2), __fmul_rn(RH0, d3)));
  float saO = __fadd_rn(__fadd_rn(__fmul_rn(RL7, a0), __fmul_rn(RL5, a1)),
                        __fadd_rn(__fmul_rn(RL3, a2), __fmul_rn(RL1, a3)));
  float sdO = __fadd_rn(__fadd_rn(__fmul_rn(RH7, d0), __fmul_rn(RH5, d1)),
                        __fadd_rn(__fmul_rn(RH3, d2), __fmul_rn(RH1, d3)));
  *ev = __fadd_rn(saE, sdE);
  *ov = __fadd_rn(saO, sdO);
}

__device__ void idwt_step(const float* __restrict__ a, const float* __restrict__ d,
                          float* __restrict__ out, int nOut, float thr,
                          bool trA, int tid) {
  int nPair = nOut >> 1;
  for (int h = tid; h < nPair; h += 256) {
    float ev, ov;
    idwt_pair_vals(a, d, h, thr, trA, &ev, &ov);
    *reinterpret_cast<float2*>(&out[2 * h]) = make_float2(ev, ov);
  }
  if (nOut & 1) {
    int h = nPair;
    if (tid == (h & 255)) {
      float ev, ov;
      idwt_pair_vals(a, d, h, thr, trA, &ev, &ov);
      out[2 * h] = ev;
    }
  }
}

__device__ void idwt_last_store(const float* __restrict__ a, const float* __restrict__ d,
                                float thr, int tid, float* __restrict__ dstRow) {
  #pragma unroll
  for (int k = 0; k < 8; ++k) {
    int h = tid + (k << 8);
    float ev, ov;
    idwt_pair_vals(a, d, h, thr, false, &ev, &ov);
    *reinterpret_cast<float2*>(&dstRow[2 * h]) = make_float2(ev, ov);
  }
}

__device__ void idwt_last_reg(const float* __restrict__ a, const float* __restrict__ d,
                              float thr, int tid, float* w) {
  #pragma unroll
  for (int k = 0; k < 8; ++k) {
    int h = tid + (k << 8);
    idwt_pair_vals(a, d, h, thr, false, &w[2 * k], &w[2 * k + 1]);
  }
}

__device__ void np_pw262_partials(const float* src, float* pbuf, int tid) {
  if (tid < 24) {
    int blk = tid >> 3, k = tid & 7;
    const float* base = src + (blk == 0 ? 0 : (blk == 1 ? 128 : 192));
    int iters = (blk == 0 ? 16 : 8);
    float r = base[k];
    for (int it = 1; it < iters; ++it) r = __fadd_rn(r, base[8 * it + k]);
    pbuf[tid] = r;
  }
}

__device__ float np_pw262_combine(const float* src, const float* pbuf) {
  float b0 = tree8(pbuf + 0);
  float b1 = tree8(pbuf + 8);
  float b2 = tree8(pbuf + 16);
  for (int i = 256; i < 262; ++i) b2 = __fadd_rn(b2, src[i]);
  return __fadd_rn(b0, __fadd_rn(b1, b2));
}

// ---------------- wavelet kernel (o0, o1, o4[; fused mask+noise]) ----------
__global__ __launch_bounds__(256)
void wavelet_kernel(const float* __restrict__ x, float* __restrict__ out0,
                    float* __restrict__ out1, float* __restrict__ out4,
                    int fuse, int at_c, int t0_c, uint32_t kcx, uint32_t kcy) {
  extern __shared__ float smem[];
  float* A  = smem;              // 4096
  float* B  = smem + 4096;       // 2052
  float* D1 = smem + 6148;       // 2052
  float* D2 = smem + 8200;       // 1030
  float* D3 = smem + 9230;       // 518
  float* D4 = smem + 9748;       // 262
  float* SC = smem + 10010;      // 2
  float* Bp = B + 512;
  const int row = blockIdx.x, tid = threadIdx.x;
  const float4* s4 = reinterpret_cast<const float4*>(x + (size_t)row * T_LEN);
  float4* o04 = reinterpret_cast<float4*>(out0 + (size_t)row * T_LEN);
  #pragma unroll
  for (int k = 0; k < 4; ++k) {
    float4 v = s4[tid + (k << 8)];
    *reinterpret_cast<float4*>(&A[4 * (tid + (k << 8))]) = v;
    o04[tid + (k << 8)] = v;
  }
  __syncthreads();
  dwt_step(A, 4096, B, D1, 2051, tid); __syncthreads();
  dwt_step(B, 2051, A, D2, 1029, tid); __syncthreads();
  dwt_step(A, 1029, B, D3, 518, tid);  __syncthreads();
  dwt_step(B, 518, A, D4, 262, tid);   __syncthreads();

  np_pw262_partials(A, Bp, tid);
  __syncthreads();
  if (tid == 0) SC[0] = np_pw262_combine(A, Bp) / 262.0f;
  __syncthreads();
  float mu = SC[0];
  for (int i = tid; i < 262; i += 256) {
    float dv = __fsub_rn(A[i], mu);
    B[i] = __fmul_rn(dv, dv);
  }
  __syncthreads();
  np_pw262_partials(B, Bp, tid);
  __syncthreads();
  if (tid == 0) SC[1] = __fsqrt_rn(np_pw262_combine(B, Bp) / 262.0f);
  __syncthreads();
  float sigma = SC[1];

  float ra0 = A[tid];
  float ra1 = (tid < 6) ? A[256 + tid] : 0.f;

  {
    float thr = __fmul_rn(0.5f, sigma);
    idwt_step(A, D4, B, 518, thr, true, tid);   __syncthreads();
    idwt_step(B, D3, A, 1029, thr, false, tid); __syncthreads();
    idwt_step(A, D2, B, 2051, thr, false, tid); __syncthreads();
    idwt_last_store(B, D1, thr, tid, out1 + (size_t)row * T_LEN);
    __syncthreads();
  }
  A[tid] = ra0;
  if (tid < 6) A[256 + tid] = ra1;
  __syncthreads();

  float thr = __fmul_rn(0.25f, sigma);
  idwt_step(A, D4, B, 518, thr, true, tid);   __syncthreads();
  idwt_step(B, D3, A, 1029, thr, false, tid); __syncthreads();
  idwt_step(A, D2, B, 2051, thr, false, tid); __syncthreads();

  float* dstRow = out4 + (size_t)row * T_LEN;
  if (!fuse) {
    idwt_last_store(B, D1, thr, tid, dstRow);
    return;
  }

  float w[16];
  idwt_last_reg(B, D1, thr, tid, w);
  if (at_c) {
    #pragma unroll
    for (int k = 0; k < 8; ++k) {
      #pragma unroll
      for (int c = 0; c < 2; ++c) {
        int col = 2 * (tid + (k << 8)) + c;
        if (col >= t0_c && col < t0_c + 204) w[2 * k + c] *= 0.1f;
      }
    }
  }
  __syncthreads();
  float* red = B;
  float acc = 0.f;
  #pragma unroll
  for (int i = 0; i < 16; ++i) acc += w[i];
  red[tid] = acc; __syncthreads();
  for (int o = 128; o > 0; o >>= 1) { if (tid < o) red[tid] += red[tid + o]; __syncthreads(); }
  float nmu = red[0] * (1.0f / 4096.0f);
  __syncthreads();
  acc = 0.f;
  #pragma unroll
  for (int i = 0; i < 16; ++i) { float dv = w[i] - nmu; acc += dv * dv; }
  red[tid] = acc; __syncthreads();
  for (int o = 128; o > 0; o >>= 1) { if (tid < o) red[tid] += red[tid + o]; __syncthreads(); }
  float nsig = sqrtf(red[0] / 4095.0f);

  #pragma unroll
  for (int k = 0; k < 8; ++k) {
    int h = tid + (k << 8);
    float o2v[2];
    #pragma unroll
    for (int c = 0; c < 2; ++c) {
      uint32_t col = (uint32_t)(2 * h + c);
      uint32_t idx = ((uint32_t)row << 12) + col;
      float z = jax_normal_from_bits(jbits_elem(kcx, kcy, idx));
      o2v[c] = w[2 * k + c] + __fmul_rn(__fmul_rn(z, 0.02f), nsig);
    }
    *reinterpret_cast<float2*>(&dstRow[2 * h]) = make_float2(o2v[0], o2v[1]);
  }
}

// ---------------- RFFT-based distortion (2048-pt complex FFT) ---------------
__constant__ int c_STW2_OFF[5] = {0, 512, 640, 672, 680};

// digit-reversed position of natural frequency k (stages r4 x5 then r2)
__device__ __forceinline__ int rev2048(int k) {
  return ((k & 3) << 9) | (((k >> 2) & 3) << 7) | (((k >> 4) & 3) << 5)
       | (((k >> 6) & 3) << 3) | (((k >> 8) & 3) << 1) | (k >> 10);
}

__device__ __forceinline__ float maskP(int K, int f0) {
  float m1 = (K >= f0 && K < f0 + 409) ? 0.1f : 1.0f;
  int K2 = (4096 - K) & 4095;
  float m2 = (K2 >= f0 && K2 < f0 + 409) ? 0.1f : 1.0f;
  return 0.5f * (m1 + m2);
}

// untangle+mask+retangle for bin k given Zk and Zm = Z[(2048-k)&2047]
__device__ __forceinline__ void retangle_one(int k, int f0,
    float zkr, float zki, float zmr, float zmi, float* outr, float* outi) {
  float xer = 0.5f * (zkr + zmr), xei = 0.5f * (zki - zmi);
  float xor_ = 0.5f * (zki + zmi), xoi = 0.5f * (zmr - zkr);
  float sn, cs;
  __sincosf((float)k * (-1.5339807878856412e-3f), &sn, &cs);  // W4096^k = (cs, sn)
  float wxr = xor_ * cs - xoi * sn, wxi = xor_ * sn + xoi * cs;
  float X1r = xer + wxr, X1i = xei + wxi;      // X[k]
  float X2r = xer - wxr, X2i = xei - wxi;      // X[k+2048]
  float m1 = maskP(k, f0), m2 = maskP(k + 2048, f0);
  X1r *= m1; X1i *= m1; X2r *= m2; X2i *= m2;
  float yer = 0.5f * (X1r + X2r), yei = 0.5f * (X1i + X2i);
  float dr = 0.5f * (X1r - X2r), di = 0.5f * (X1i - X2i);
  float yor = dr * cs + di * sn, yoi = di * cs - dr * sn;  // W^{-k}*(X1-X2)/2
  *outr = yer - yoi; *outi = yei + yor;        // Ye + i*Yo
}

// distort row (af branch: RFFT pipeline); results into w[16] (same layout as r10)
__device__ void distort_core(float* smem, const float4* v4, float* w,
                             int af, int f0, int at, int t0, int tid) {
  float* RE = smem;                    // PD(2048) -> 2112
  float* IM = smem + 2112;             // 2112
  float2* STW = (float2*)(smem + 4224);// 682 entries
  if (af) {
    // stage-sequential twiddles: W_2048^e, e = j << (2s)
    for (int t = tid; t < 682; t += 256) {
      int s, j;
      if (t < 512) { s = 0; j = t; }
      else if (t < 640) { s = 1; j = t - 512; }
      else if (t < 672) { s = 2; j = t - 640; }
      else if (t < 680) { s = 3; j = t - 672; }
      else { s = 4; j = t - 680; }
      int e = j << (2 * s);
      float ang = (float)e * (-3.0679615757712823e-3f);  // -2pi/2048
      float sn, cs;
      __sincosf(ang, &sn, &cs);
      STW[t] = make_float2(cs, sn);
    }
    // pack z[n] = x[2n] + i x[2n+1]
    #pragma unroll
    for (int k = 0; k < 4; ++k) {
      int n = 2 * (tid + (k << 8));
      RE[PD(n)]     = v4[k].x; IM[PD(n)]     = v4[k].y;
      RE[PD(n + 1)] = v4[k].z; IM[PD(n + 1)] = v4[k].w;
    }
    __syncthreads();
    // forward: 5 radix-4 DIF stages (L = 2048..8)
    for (int s = 0; s < 5; ++s) {
      int Lsh = 11 - 2 * s, Qsh = Lsh - 2, Qm = (1 << Qsh) - 1, off = c_STW2_OFF[s];
      for (int b = tid; b < 512; b += 256) {
        int j = b & Qm, g = b >> Qsh;
        int i0 = (g << Lsh) + j;
        int i1 = i0 + (1 << Qsh), i2 = i1 + (1 << Qsh), i3 = i2 + (1 << Qsh);
        float x0r = RE[PD(i0)], x0i = IM[PD(i0)];
        float x1r = RE[PD(i1)], x1i = IM[PD(i1)];
        float x2r = RE[PD(i2)], x2i = IM[PD(i2)];
        float x3r = RE[PD(i3)], x3i = IM[PD(i3)];
        float t0r = x0r + x2r, t0i = x0i + x2i;
        float t1r = x0r - x2r, t1i = x0i - x2i;
        float t2r = x1r + x3r, t2i = x1i + x3i;
        float t3r = x1r - x3r, t3i = x1i - x3i;
        float2 w1 = STW[off + j];
        float c1 = w1.x, s1 = w1.y;
        float c2 = c1 * c1 - s1 * s1, s2 = 2.f * c1 * s1;
        float c3 = c1 * c2 - s1 * s2, s3 = c1 * s2 + s1 * c2;
        RE[PD(i0)] = t0r + t2r; IM[PD(i0)] = t0i + t2i;
        float u1r = t1r + t3i, u1i = t1i - t3r;
        RE[PD(i1)] = u1r * c1 - u1i * s1; IM[PD(i1)] = u1r * s1 + u1i * c1;
        float u2r = t0r - t2r, u2i = t0i - t2i;
        RE[PD(i2)] = u2r * c2 - u2i * s2; IM[PD(i2)] = u2r * s2 + u2i * c2;
        float u3r = t1r - t3i, u3i = t1i + t3r;
        RE[PD(i3)] = u3r * c3 - u3i * s3; IM[PD(i3)] = u3r * s3 + u3i * c3;
      }
      __syncthreads();
    }
    // final radix-2 stage (L=2, twiddle-free)
    for (int m = tid; m < 1024; m += 256) {
      int i0 = 2 * m, i1 = 2 * m + 1;
      float ar = RE[PD(i0)], ai = IM[PD(i0)];
      float br = RE[PD(i1)], bi = IM[PD(i1)];
      RE[PD(i0)] = ar + br; IM[PD(i0)] = ai + bi;
      RE[PD(i1)] = ar - br; IM[PD(i1)] = ai - bi;
    }
    __syncthreads();
    // middle: untangle + fold-mask + retangle, in-place at digit-rev positions
    for (int k0 = tid; k0 < 1024; k0 += 256) {
      if (k0 == 0) {
        {
          int pk = PD(rev2048(0));
          float zr = RE[pk], zi = IM[pk], orr, oi;
          retangle_one(0, f0, zr, zi, zr, zi, &orr, &oi);
          RE[pk] = orr; IM[pk] = oi;
        }
        {
          int pk = PD(rev2048(1024));
          float zr = RE[pk], zi = IM[pk], orr, oi;
          retangle_one(1024, f0, zr, zi, zr, zi, &orr, &oi);
          RE[pk] = orr; IM[pk] = oi;
        }
      } else {
        int m = 2048 - k0;
        int pk = PD(rev2048(k0)), pm = PD(rev2048(m));
        float zkr = RE[pk], zki = IM[pk];
        float zmr = RE[pm], zmi = IM[pm];
        float akr, aki, amr, ami;
        retangle_one(k0, f0, zkr, zki, zmr, zmi, &akr, &aki);
        retangle_one(m, f0, zmr, zmi, zkr, zki, &amr, &ami);
        RE[pk] = akr; IM[pk] = aki;
        RE[pm] = amr; IM[pm] = ami;
      }
    }
    __syncthreads();
    // inverse: radix-2 first, then 5 radix-4 DIT stages (conj twiddles)
    for (int m = tid; m < 1024; m += 256) {
      int i0 = 2 * m, i1 = 2 * m + 1;
      float ar = RE[PD(i0)], ai = IM[PD(i0)];
      float br = RE[PD(i1)], bi = IM[PD(i1)];
      RE[PD(i0)] = ar + br; IM[PD(i0)] = ai + bi;
      RE[PD(i1)] = ar - br; IM[PD(i1)] = ai - bi;
    }
    __syncthreads();
    for (int s = 4; s >= 0; --s) {
      int Lsh = 11 - 2 * s, Qsh = Lsh - 2, Qm = (1 << Qsh) - 1, off = c_STW2_OFF[s];
      for (int b = tid; b < 512; b += 256) {
        int j = b & Qm, g = b >> Qsh;
        int i0 = (g << Lsh) + j;
        int i1 = i0 + (1 << Qsh), i2 = i1 + (1 << Qsh), i3 = i2 + (1 << Qsh);
        float y0r = RE[PD(i0)], y0i = IM[PD(i0)];
        float y1r = RE[PD(i1)], y1i = IM[PD(i1)];
        float y2r = RE[PD(i2)], y2i = IM[PD(i2)];
        float y3r = RE[PD(i3)], y3i = IM[PD(i3)];
        float2 w1 = STW[off + j];
        float c1 = w1.x, s1 = -w1.y;
        float c2 = c1 * c1 - s1 * s1, s2 = 2.f * c1 * s1;
        float c3 = c1 * c2 - s1 * s2, s3 = c1 * s2 + s1 * c2;
        float z1r = y1r * c1 - y1i * s1, z1i = y1r * s1 + y1i * c1;
        float z2r = y2r * c2 - y2i * s2, z2i = y2r * s2 + y2i * c2;
        float z3r = y3r * c3 - y3i * s3, z3i = y3r * s3 + y3i * c3;
        float u0r = y0r + z2r, u0i = y0i + z2i;
        float u2r = y0r - z2r, u2i = y0i - z2i;
        float u1r = z1r + z3r, u1i = z1i + z3i;
        float u3r = z3i - z1i, u3i = z1r - z3r;
        RE[PD(i0)] = u0r + u1r; IM[PD(i0)] = u0i + u1i;
        RE[PD(i1)] = u2r + u3r; IM[PD(i1)] = u2i + u3i;
        RE[PD(i2)] = u0r - u1r; IM[PD(i2)] = u0i - u1i;
        RE[PD(i3)] = u2r - u3r; IM[PD(i3)] = u2i - u3i;
      }
      __syncthreads();
    }
    // unpack: xd[2n] = Re z'[n]/2048, xd[2n+1] = Im z'[n]/2048
    #pragma unroll
    for (int k = 0; k < 4; ++k) {
      int n = 2 * (tid + (k << 8));
      w[4 * k + 0] = RE[PD(n)]     * (1.0f / 2048.0f);
      w[4 * k + 1] = IM[PD(n)]     * (1.0f / 2048.0f);
      w[4 * k + 2] = RE[PD(n + 1)] * (1.0f / 2048.0f);
      w[4 * k + 3] = IM[PD(n + 1)] * (1.0f / 2048.0f);
    }
    __syncthreads();
  } else {
    #pragma unroll
    for (int k = 0; k < 4; ++k) {
      w[4 * k + 0] = v4[k].x; w[4 * k + 1] = v4[k].y;
      w[4 * k + 2] = v4[k].z; w[4 * k + 3] = v4[k].w;
    }
  }
  if (at) {
    #pragma unroll
    for (int i = 0; i < 16; ++i) {
      int col = 4 * (tid + ((i >> 2) << 8)) + (i & 3);
      if (col >= t0 && col < t0 + 204) w[i] *= 0.1f;
    }
  }
}

__global__ __launch_bounds__(256)
void distort_noise_kernel(const float* __restrict__ src, float* __restrict__ dst_d,
                          float* __restrict__ dst_n,
                          int af, int f0, int at, int t0, int nod, int wd,
                          uint32_t kx, uint32_t ky) {
  extern __shared__ float smem[];
  const int row = blockIdx.x, tid = threadIdx.x;

  const float4* s4 = reinterpret_cast<const float4*>(src + (size_t)row * T_LEN);
  float4 v4[4];
  #pragma unroll
  for (int k = 0; k < 4; ++k) v4[k] = s4[tid + (k << 8)];

  float w[16];
  distort_core(smem, v4, w, af, f0, at, t0, tid);

  if (wd) {
    float4* d4 = reinterpret_cast<float4*>(dst_d + (size_t)row * T_LEN);
    #pragma unroll
    for (int k = 0; k < 4; ++k)
      d4[tid + (k << 8)] = make_float4(w[4 * k], w[4 * k + 1], w[4 * k + 2], w[4 * k + 3]);
  }

  float nv[16];
  #pragma unroll
  for (int i = 0; i < 16; ++i) {
    float q;
    if (nod) q = w[i];
    else {
      float4 vv = v4[i >> 2];
      q = (i & 3) == 0 ? vv.x : (i & 3) == 1 ? vv.y : (i & 3) == 2 ? vv.z : vv.w;
    }
    nv[i] = q;
  }
  float* red = smem;
  float acc = 0.f;
  #pragma unroll
  for (int i = 0; i < 16; ++i) acc += nv[i];
  red[tid] = acc; __syncthreads();
  for (int o = 128; o > 0; o >>= 1) { if (tid < o) red[tid] += red[tid + o]; __syncthreads(); }
  float mu = red[0] * (1.0f / 4096.0f);
  __syncthreads();
  acc = 0.f;
  #pragma unroll
  for (int i = 0; i < 16; ++i) { float dv = nv[i] - mu; acc += dv * dv; }
  red[tid] = acc; __syncthreads();
  for (int o = 128; o > 0; o >>= 1) { if (tid < o) red[tid] += red[tid + o]; __syncthreads(); }
  float sigma = sqrtf(red[0] / 4095.0f);

  float4* n4 = reinterpret_cast<float4*>(dst_n + (size_t)row * T_LEN);
  #pragma unroll
  for (int k = 0; k < 4; ++k) {
    float o[4];
    #pragma unroll
    for (int c = 0; c < 4; ++c) {
      uint32_t col = (uint32_t)(4 * (tid + (k << 8)) + c);
      uint32_t idx = ((uint32_t)row << 12) + col;
      float z = jax_normal_from_bits(jbits_elem(kx, ky, idx));
      o[c] = nv[4 * k + c] + __fmul_rn(__fmul_rn(z, 0.02f), sigma);
    }
    n4[tid + (k << 8)] = make_float4(o[0], o[1], o[2], o[3]);
  }
}

// ---------------- launcher ----------------
extern "C" void kernel_launch(void* const* d_in, const int* in_sizes, int n_in,
                              void* d_out, int out_size, void* d_ws, size_t ws_size,
                              hipStream_t stream) {
  const float* x = (const float*)d_in[0];
  float* out = (float*)d_out;
  float* o0 = out;
  float* o1 = out + (size_t)N_ELEM;
  float* o2 = out + 2 * (size_t)N_ELEM;
  float* o3 = out + 3 * (size_t)N_ELEM;
  float* o4 = out + 4 * (size_t)N_ELEM;

  uint32_t r[8];
  jsplit4(0u, 42u, r);  // kd, kn, kcd, kcn
  int f0d, afd, t0d, atd, f0c, afc, t0c, atc;
  distort_params(r[0], r[1], &f0d, &afd, &t0d, &atd);
  distort_params(r[4], r[5], &f0c, &afc, &t0c, &atc);

  const size_t WAVE_LDS = 10012u * 4u;   // 40048 B -> 4 blocks/CU
  const size_t FFT_LDS  = 5588u * 4u;    // 22352 B -> 7 blocks/CU

  hipLaunchKernelGGL(wavelet_kernel, dim3(N_ROWS), dim3(256), WAVE_LDS, stream,
                     x, o0, o1, o4, afc ? 0 : 1, atc, t0c, r[6], r[7]);
  hipLaunchKernelGGL(distort_noise_kernel, dim3(N_ROWS), dim3(256),
                     afd ? FFT_LDS : 1024, stream,
                     x, o2, o3, afd, f0d, atd, t0d, 0, 1, r[2], r[3]);
  if (afc) {
    hipLaunchKernelGGL(distort_noise_kernel, dim3(N_ROWS), dim3(256), FFT_LDS, stream,
                       o4, o4, o4, 1, f0c, atc, t0c, 1, 0, r[6], r[7]);
  }
}

// Round 12
// 273.718 us; speedup vs baseline: 1.3130x; 1.0226x over previous
//
#include <hip/hip_runtime.h>
#include <stdint.h>

#define T_LEN 4096
#define N_ROWS 4096
#define N_ELEM (4096u * 4096u)
#define PD(i) ((i) + ((i) >> 5))

// ---------------- wavelet filters (db4) ----------------
__constant__ float c_DEC_LO[8] = {
  -0.010597401785069032f, 0.0328830116668852f, 0.030841381835560764f,
  -0.18703481171909309f, -0.027983769416859854f, 0.6308807679298589f,
   0.7148465705529157f, 0.2303778133088965f };
__constant__ float c_DEC_HI[8] = {
  -0.2303778133088965f, 0.7148465705529157f, -0.6308807679298589f,
  -0.027983769416859854f, 0.18703481171909309f, 0.030841381835560764f,
  -0.0328830116668852f, -0.010597401785069032f };

#define RL0 0.2303778133088965f
#define RL1 0.7148465705529157f
#define RL2 0.6308807679298589f
#define RL3 (-0.027983769416859854f)
#define RL4 (-0.18703481171909309f)
#define RL5 0.030841381835560764f
#define RL6 0.0328830116668852f
#define RL7 (-0.010597401785069032f)
#define RH0 (-0.010597401785069032f)
#define RH1 (-0.0328830116668852f)
#define RH2 0.030841381835560764f
#define RH3 0.18703481171909309f
#define RH4 (-0.027983769416859854f)
#define RH5 (-0.6308807679298589f)
#define RH6 0.7148465705529157f
#define RH7 (-0.2303778133088965f)

// ---------------- Threefry-2x32 (host+device) ----------------
__host__ __device__ __forceinline__ uint32_t rotl32(uint32_t v, int r) {
  return (v << r) | (v >> (32 - r));
}

__host__ __device__ __forceinline__ void tf2x32(uint32_t k0, uint32_t k1,
                                                uint32_t c0, uint32_t c1,
                                                uint32_t& o0, uint32_t& o1) {
  uint32_t ks2 = k0 ^ k1 ^ 0x1BD11BDAu;
  uint32_t x0 = c0 + k0;
  uint32_t x1 = c1 + k1;
#define TFR(r) { x0 += x1; x1 = rotl32(x1, r); x1 ^= x0; }
  TFR(13) TFR(15) TFR(26) TFR(6)
  x0 += k1;  x1 += ks2 + 1u;
  TFR(17) TFR(29) TFR(16) TFR(24)
  x0 += ks2; x1 += k0 + 2u;
  TFR(13) TFR(15) TFR(26) TFR(6)
  x0 += k0;  x1 += k1 + 3u;
  TFR(17) TFR(29) TFR(16) TFR(24)
  x0 += k1;  x1 += ks2 + 4u;
  TFR(13) TFR(15) TFR(26) TFR(6)
  x0 += ks2; x1 += k0 + 5u;
#undef TFR
  o0 = x0; o1 = x1;
}

__host__ __device__ __forceinline__ uint32_t jbits_scalar(uint32_t kx, uint32_t ky) {
  uint32_t a, b; tf2x32(kx, ky, 0u, 0u, a, b);
  return a ^ b;
}

__device__ __forceinline__ uint32_t jbits_elem(uint32_t kx, uint32_t ky, uint32_t i) {
  uint32_t a, b; tf2x32(kx, ky, 0u, i, a, b); return a ^ b;
}

__host__ __device__ __forceinline__ float junif_scalar(uint32_t kx, uint32_t ky) {
  union { uint32_t u; float f; } cv;
  cv.u = (jbits_scalar(kx, ky) >> 9) | 0x3f800000u;
  return cv.f - 1.0f;
}

__host__ __device__ __forceinline__ void jsplit2(uint32_t kx, uint32_t ky, uint32_t* o) {
  tf2x32(kx, ky, 0u, 0u, o[0], o[1]);
  tf2x32(kx, ky, 0u, 1u, o[2], o[3]);
}

__host__ __device__ __forceinline__ void jsplit4(uint32_t kx, uint32_t ky, uint32_t* o) {
  tf2x32(kx, ky, 0u, 0u, o[0], o[1]);
  tf2x32(kx, ky, 0u, 1u, o[2], o[3]);
  tf2x32(kx, ky, 0u, 2u, o[4], o[5]);
  tf2x32(kx, ky, 0u, 3u, o[6], o[7]);
}

__host__ __device__ __forceinline__ int jrandint(uint32_t kx, uint32_t ky, uint32_t span) {
  uint32_t c[4];
  jsplit2(kx, ky, c);
  uint32_t hi = jbits_scalar(c[0], c[1]);
  uint32_t lo = jbits_scalar(c[2], c[3]);
  uint32_t mult = 65536u % span;
  mult = (mult * mult) % span;
  uint32_t off = ((hi % span) * mult + (lo % span)) % span;
  return (int)off;
}

__host__ __device__ void distort_params(uint32_t kx, uint32_t ky,
                                        int* f0, int* af, int* t0, int* at) {
  uint32_t q[8];
  jsplit4(kx, ky, q);
  *af = junif_scalar(q[0], q[1]) < 0.3f;
  *f0 = jrandint(q[2], q[3], 3687u);
  *at = junif_scalar(q[4], q[5]) < 0.3f;
  *t0 = jrandint(q[6], q[7], 3892u);
}

__device__ __forceinline__ float erfinv32(float x) {
  float w = -log1pf(-x * x);
  float p;
  if (w < 5.0f) {
    w = w - 2.5f;
    p = 2.81022636e-08f;
    p = fmaf(p, w, 3.43273939e-07f);
    p = fmaf(p, w, -3.5233877e-06f);
    p = fmaf(p, w, -4.39150654e-06f);
    p = fmaf(p, w, 0.00021858087f);
    p = fmaf(p, w, -0.00125372503f);
    p = fmaf(p, w, -0.00417768164f);
    p = fmaf(p, w, 0.246640727f);
    p = fmaf(p, w, 1.50140941f);
  } else {
    w = sqrtf(w) - 3.0f;
    p = -0.000200214257f;
    p = fmaf(p, w, 0.000100950558f);
    p = fmaf(p, w, 0.00134934322f);
    p = fmaf(p, w, -0.00367342844f);
    p = fmaf(p, w, 0.00573950773f);
    p = fmaf(p, w, -0.0076224613f);
    p = fmaf(p, w, 0.00943887047f);
    p = fmaf(p, w, 1.00167406f);
    p = fmaf(p, w, 2.83297682f);
  }
  return p * x;
}

__device__ __forceinline__ float jax_normal_from_bits(uint32_t bits) {
  union { uint32_t u; float f; } cv;
  cv.u = (bits >> 9) | 0x3f800000u;
  float f = cv.f - 1.0f;
  const float lo = -0.99999994f;
  float u = __fadd_rn(__fmul_rn(f, 2.0f), lo);
  u = fmaxf(lo, u);
  return 1.41421356f * erfinv32(u);
}

// numpy tree-of-8 sum
__device__ __forceinline__ float tree8(const float* p) {
  return __fadd_rn(
      __fadd_rn(__fadd_rn(p[0], p[1]), __fadd_rn(p[2], p[3])),
      __fadd_rn(__fadd_rn(p[4], p[5]), __fadd_rn(p[6], p[7])));
}

// ---------------- wavelet primitives (per-output arithmetic bit-exact) -----
__device__ __forceinline__ void dwt_one(const float* a, int n, int i,
                                        float* oA, float* oD) {
  int base = 2 * i - 6;
  float pa[8], pd[8];
  #pragma unroll
  for (int j = 0; j < 8; ++j) {
    int q = base + j;
    q = (q < 0) ? (-q - 1) : ((q >= n) ? (2 * n - 1 - q) : q);
    float xv = a[q];
    pa[j] = __fmul_rn(c_DEC_LO[7 - j], xv);
    pd[j] = __fmul_rn(c_DEC_HI[7 - j], xv);
  }
  *oA = tree8(pa); *oD = tree8(pd);
}

// 4 consecutive interior outputs i0..i0+3 (requires i0 mult of 4, i0>=4,
// 2*i0+7 <= n-1). Window loaded as 4x float4 from a[2*i0-8 ..].
__device__ __forceinline__ void dwt_chunk4(const float* a, int i0,
                                           float* oa, float* od) {
  const float4* ap = reinterpret_cast<const float4*>(a + 2 * i0 - 8);
  float4 v0 = ap[0], v1 = ap[1], v2 = ap[2], v3 = ap[3];
  float x[16] = {v0.x, v0.y, v0.z, v0.w, v1.x, v1.y, v1.z, v1.w,
                 v2.x, v2.y, v2.z, v2.w, v3.x, v3.y, v3.z, v3.w};
  float ra[4], rd[4];
  #pragma unroll
  for (int p = 0; p < 4; ++p) {
    float pa[8], pd[8];
    #pragma unroll
    for (int j = 0; j < 8; ++j) {
      float xv = x[2 * p + 2 + j];
      pa[j] = __fmul_rn(c_DEC_LO[7 - j], xv);
      pd[j] = __fmul_rn(c_DEC_HI[7 - j], xv);
    }
    ra[p] = tree8(pa); rd[p] = tree8(pd);
  }
  *reinterpret_cast<float4*>(&oa[i0]) = make_float4(ra[0], ra[1], ra[2], ra[3]);
  *reinterpret_cast<float4*>(&od[i0]) = make_float4(rd[0], rd[1], rd[2], rd[3]);
}

// generic pair-based dwt (small levels)
__device__ void dwt_step(const float* a, int n, float* oa, float* od,
                         int nOut, int tid) {
  int iHi = (n - 2) >> 1;
  int nPair = nOut >> 1;
  for (int u = tid; u < nPair; u += 256) {
    int i0 = 2 * u;
    if (u >= 2 && (i0 + 1) <= iHi) {
      int base = 2 * i0 - 6;
      float x[10];
      #pragma unroll
      for (int j = 0; j < 10; ++j) x[j] = a[base + j];
      float p0[8], p1[8], q0[8], q1[8];
      #pragma unroll
      for (int j = 0; j < 8; ++j) {
        p0[j] = __fmul_rn(c_DEC_LO[7 - j], x[j]);
        q0[j] = __fmul_rn(c_DEC_HI[7 - j], x[j]);
        p1[j] = __fmul_rn(c_DEC_LO[7 - j], x[j + 2]);
        q1[j] = __fmul_rn(c_DEC_HI[7 - j], x[j + 2]);
      }
      *reinterpret_cast<float2*>(&oa[i0]) = make_float2(tree8(p0), tree8(p1));
      *reinterpret_cast<float2*>(&od[i0]) = make_float2(tree8(q0), tree8(q1));
    } else {
      float a0, d0, a1, d1;
      dwt_one(a, n, i0, &a0, &d0);
      dwt_one(a, n, i0 + 1, &a1, &d1);
      oa[i0] = a0; od[i0] = d0;
      oa[i0 + 1] = a1; od[i0 + 1] = d1;
    }
  }
  for (int i = 2 * nPair + tid; i < nOut; i += 256) {
    float av, dv;
    dwt_one(a, n, i, &av, &dv);
    oa[i] = av; od[i] = dv;
  }
}

__device__ __forceinline__ void idwt_pair_vals(const float* __restrict__ a,
                                               const float* __restrict__ d,
                                               int h, float thr, bool trA,
                                               float* ev, float* ov) {
  float a0 = a[h], a1 = a[h + 1], a2 = a[h + 2], a3 = a[h + 3];
  if (trA) {
    a0 = (fabsf(a0) < thr) ? 0.f : a0;
    a1 = (fabsf(a1) < thr) ? 0.f : a1;
    a2 = (fabsf(a2) < thr) ? 0.f : a2;
    a3 = (fabsf(a3) < thr) ? 0.f : a3;
  }
  float d0 = d[h], d1 = d[h + 1], d2 = d[h + 2], d3 = d[h + 3];
  d0 = (fabsf(d0) < thr) ? 0.f : d0;
  d1 = (fabsf(d1) < thr) ? 0.f : d1;
  d2 = (fabsf(d2) < thr) ? 0.f : d2;
  d3 = (fabsf(d3) < thr) ? 0.f : d3;
  float saE = __fadd_rn(__fadd_rn(__fmul_rn(RL6, a0), __fmul_rn(RL4, a1)),
                        __fadd_rn(__fmul_rn(RL2, a2), __fmul_rn(RL0, a3)));
  float sdE = __fadd_rn(__fadd_rn(__fmul_rn(RH6, d0), __fmul_rn(RH4, d1)),
                        __fadd_rn(__fmul_rn(RH2, d2), __fmul_rn(RH0, d3)));
  float saO = __fadd_rn(__fadd_rn(__fmul_rn(RL7, a0), __fmul_rn(RL5, a1)),
                        __fadd_rn(__fmul_rn(RL3, a2), __fmul_rn(RL1, a3)));
  float sdO = __fadd_rn(__fadd_rn(__fmul_rn(RH7, d0), __fmul_rn(RH5, d1)),
                        __fadd_rn(__fmul_rn(RH3, d2), __fmul_rn(RH1, d3)));
  *ev = __fadd_rn(saE, sdE);
  *ov = __fadd_rn(saO, sdO);
}

// 4 consecutive pairs h0..h0+3 (h0 mult of 4). Loads 8 a + 8 d via float4;
// element [7] is loaded but unused in arithmetic (pair p uses A8[p..p+3]).
__device__ __forceinline__ void idwt_chunk4(const float* __restrict__ a,
                                            const float* __restrict__ d,
                                            int h0, float thr, bool trA,
                                            float* o8) {
  float4 va0 = *reinterpret_cast<const float4*>(a + h0);
  float4 va1 = *reinterpret_cast<const float4*>(a + h0 + 4);
  float4 vd0 = *reinterpret_cast<const float4*>(d + h0);
  float4 vd1 = *reinterpret_cast<const float4*>(d + h0 + 4);
  float A8[8] = {va0.x, va0.y, va0.z, va0.w, va1.x, va1.y, va1.z, va1.w};
  float D8[8] = {vd0.x, vd0.y, vd0.z, vd0.w, vd1.x, vd1.y, vd1.z, vd1.w};
  if (trA) {
    #pragma unroll
    for (int j = 0; j < 8; ++j) A8[j] = (fabsf(A8[j]) < thr) ? 0.f : A8[j];
  }
  #pragma unroll
  for (int j = 0; j < 8; ++j) D8[j] = (fabsf(D8[j]) < thr) ? 0.f : D8[j];
  #pragma unroll
  for (int p = 0; p < 4; ++p) {
    float a0 = A8[p], a1 = A8[p + 1], a2 = A8[p + 2], a3 = A8[p + 3];
    float d0 = D8[p], d1 = D8[p + 1], d2 = D8[p + 2], d3 = D8[p + 3];
    float saE = __fadd_rn(__fadd_rn(__fmul_rn(RL6, a0), __fmul_rn(RL4, a1)),
                          __fadd_rn(__fmul_rn(RL2, a2), __fmul_rn(RL0, a3)));
    float sdE = __fadd_rn(__fadd_rn(__fmul_rn(RH6, d0), __fmul_rn(RH4, d1)),
                          __fadd_rn(__fmul_rn(RH2, d2), __fmul_rn(RH0, d3)));
    float saO = __fadd_rn(__fadd_rn(__fmul_rn(RL7, a0), __fmul_rn(RL5, a1)),
                          __fadd_rn(__fmul_rn(RL3, a2), __fmul_rn(RL1, a3)));
    float sdO = __fadd_rn(__fadd_rn(__fmul_rn(RH7, d0), __fmul_rn(RH5, d1)),
                          __fadd_rn(__fmul_rn(RH3, d2), __fmul_rn(RH1, d3)));
    o8[2 * p]     = __fadd_rn(saE, sdE);
    o8[2 * p + 1] = __fadd_rn(saO, sdO);
  }
}

// generic pair idwt (small levels)
__device__ void idwt_step(const float* __restrict__ a, const float* __restrict__ d,
                          float* __restrict__ out, int nOut, float thr,
                          bool trA, int tid) {
  int nPair = nOut >> 1;
  for (int h = tid; h < nPair; h += 256) {
    float ev, ov;
    idwt_pair_vals(a, d, h, thr, trA, &ev, &ov);
    *reinterpret_cast<float2*>(&out[2 * h]) = make_float2(ev, ov);
  }
  if (nOut & 1) {
    int h = nPair;
    if (tid == (h & 255)) {
      float ev, ov;
      idwt_pair_vals(a, d, h, thr, trA, &ev, &ov);
      out[2 * h] = ev;
    }
  }
}

__device__ void np_pw262_partials(const float* src, float* pbuf, int tid) {
  if (tid < 24) {
    int blk = tid >> 3, k = tid & 7;
    const float* base = src + (blk == 0 ? 0 : (blk == 1 ? 128 : 192));
    int iters = (blk == 0 ? 16 : 8);
    float r = base[k];
    for (int it = 1; it < iters; ++it) r = __fadd_rn(r, base[8 * it + k]);
    pbuf[tid] = r;
  }
}

__device__ float np_pw262_combine(const float* src, const float* pbuf) {
  float b0 = tree8(pbuf + 0);
  float b1 = tree8(pbuf + 8);
  float b2 = tree8(pbuf + 16);
  for (int i = 256; i < 262; ++i) b2 = __fadd_rn(b2, src[i]);
  return __fadd_rn(b0, __fadd_rn(b1, b2));
}

// ---------------- wavelet kernel (o0, o1, o4[; fused mask+noise]) ----------
__global__ __launch_bounds__(256, 4)
void wavelet_kernel(const float* __restrict__ x, float* __restrict__ out0,
                    float* __restrict__ out1, float* __restrict__ out4,
                    int fuse, int at_c, int t0_c, uint32_t kcx, uint32_t kcy) {
  extern __shared__ float smem[];
  float* A  = smem;              // 4096
  float* B  = smem + 4096;       // 2052
  float* D1 = smem + 6148;       // 2052
  float* D2 = smem + 8200;       // 1030
  float* D3 = smem + 9230;       // 518
  float* D4 = smem + 9748;       // 262
  float* SC = smem + 10010;      // 2
  float* Bp = B + 512;
  const int row = blockIdx.x, tid = threadIdx.x;
  const float4* s4 = reinterpret_cast<const float4*>(x + (size_t)row * T_LEN);
  float4* o04 = reinterpret_cast<float4*>(out0 + (size_t)row * T_LEN);
  #pragma unroll
  for (int k = 0; k < 4; ++k) {
    float4 v = s4[tid + (k << 8)];
    *reinterpret_cast<float4*>(&A[4 * (tid + (k << 8))]) = v;
    o04[tid + (k << 8)] = v;
  }
  __syncthreads();

  // ---- dwt level 1: A(4096) -> B(2051), D1(2051) ----
  if (tid == 0) {
    #pragma unroll
    for (int i = 0; i < 4; ++i) {
      float av, dv; dwt_one(A, 4096, i, &av, &dv); B[i] = av; D1[i] = dv;
    }
  } else {
    dwt_chunk4(A, 4 * tid, B, D1);          // i0 = 4..1020
  }
  dwt_chunk4(A, 1024 + 4 * tid, B, D1);     // i0 = 1024..2044
  if (tid < 3) {
    float av, dv; dwt_one(A, 4096, 2048 + tid, &av, &dv);
    B[2048 + tid] = av; D1[2048 + tid] = dv;
  }
  __syncthreads();

  // ---- dwt level 2: B(2051) -> A(1029), D2(1029) ----
  if (tid == 0) {
    #pragma unroll
    for (int i = 0; i < 4; ++i) {
      float av, dv; dwt_one(B, 2051, i, &av, &dv); A[i] = av; D2[i] = dv;
    }
  } else {
    dwt_chunk4(B, 4 * tid, A, D2);          // i0 = 4..1020
  }
  if (tid < 5) {
    float av, dv; dwt_one(B, 2051, 1024 + tid, &av, &dv);
    A[1024 + tid] = av; D2[1024 + tid] = dv;
  }
  __syncthreads();

  // ---- dwt levels 3,4 (small, generic) ----
  dwt_step(A, 1029, B, D3, 518, tid);  __syncthreads();
  dwt_step(B, 518, A, D4, 262, tid);   __syncthreads();   // a4 -> A[0:262)

  // ---- sigma(a4), ddof=0, exact numpy pairwise order ----
  np_pw262_partials(A, Bp, tid);
  __syncthreads();
  if (tid == 0) SC[0] = np_pw262_combine(A, Bp) / 262.0f;
  __syncthreads();
  float mu = SC[0];
  for (int i = tid; i < 262; i += 256) {
    float dv = __fsub_rn(A[i], mu);
    B[i] = __fmul_rn(dv, dv);
  }
  __syncthreads();
  np_pw262_partials(B, Bp, tid);
  __syncthreads();
  if (tid == 0) SC[1] = __fsqrt_rn(np_pw262_combine(B, Bp) / 262.0f);
  __syncthreads();
  float sigma = SC[1];

  float ra0 = A[tid];
  float ra1 = (tid < 6) ? A[256 + tid] : 0.f;

  // ---- v = 0 : thr = 0.5*sigma -> out1 ----
  {
    float thr = __fmul_rn(0.5f, sigma);
    idwt_step(A, D4, B, 518, thr, true, tid);   __syncthreads();
    idwt_step(B, D3, A, 1029, thr, false, tid); __syncthreads();
    // 2051-level wide: pairs 0..1023 via chunks, then remainder
    {
      float o8[8];
      idwt_chunk4(A, D2, 4 * tid, thr, false, o8);
      *reinterpret_cast<float4*>(&B[8 * tid])     = make_float4(o8[0], o8[1], o8[2], o8[3]);
      *reinterpret_cast<float4*>(&B[8 * tid + 4]) = make_float4(o8[4], o8[5], o8[6], o8[7]);
      if (tid == 0) {
        float ev, ov;
        idwt_pair_vals(A, D2, 1024, thr, false, &ev, &ov);
        B[2048] = ev; B[2049] = ov;
      } else if (tid == 1) {
        float ev, ov;
        idwt_pair_vals(A, D2, 1025, thr, false, &ev, &ov);
        B[2050] = ev;
      }
    }
    __syncthreads();
    // last level wide -> global out1
    float* dstRow = out1 + (size_t)row * T_LEN;
    float o8[8];
    idwt_chunk4(B, D1, 4 * tid, thr, false, o8);
    *reinterpret_cast<float4*>(&dstRow[8 * tid])     = make_float4(o8[0], o8[1], o8[2], o8[3]);
    *reinterpret_cast<float4*>(&dstRow[8 * tid + 4]) = make_float4(o8[4], o8[5], o8[6], o8[7]);
    idwt_chunk4(B, D1, 1024 + 4 * tid, thr, false, o8);
    *reinterpret_cast<float4*>(&dstRow[2048 + 8 * tid])     = make_float4(o8[0], o8[1], o8[2], o8[3]);
    *reinterpret_cast<float4*>(&dstRow[2048 + 8 * tid + 4]) = make_float4(o8[4], o8[5], o8[6], o8[7]);
  }
  __syncthreads();
  A[tid] = ra0;
  if (tid < 6) A[256 + tid] = ra1;
  __syncthreads();

  // ---- v = 1 : thr = 0.25*sigma -> out4 ----
  float thr = __fmul_rn(0.25f, sigma);
  idwt_step(A, D4, B, 518, thr, true, tid);   __syncthreads();
  idwt_step(B, D3, A, 1029, thr, false, tid); __syncthreads();
  {
    float o8[8];
    idwt_chunk4(A, D2, 4 * tid, thr, false, o8);
    *reinterpret_cast<float4*>(&B[8 * tid])     = make_float4(o8[0], o8[1], o8[2], o8[3]);
    *reinterpret_cast<float4*>(&B[8 * tid + 4]) = make_float4(o8[4], o8[5], o8[6], o8[7]);
    if (tid == 0) {
      float ev, ov;
      idwt_pair_vals(A, D2, 1024, thr, false, &ev, &ov);
      B[2048] = ev; B[2049] = ov;
    } else if (tid == 1) {
      float ev, ov;
      idwt_pair_vals(A, D2, 1025, thr, false, &ev, &ov);
      B[2050] = ev;
    }
  }
  __syncthreads();

  float* dstRow = out4 + (size_t)row * T_LEN;
  if (!fuse) {
    float o8[8];
    idwt_chunk4(B, D1, 4 * tid, thr, false, o8);
    *reinterpret_cast<float4*>(&dstRow[8 * tid])     = make_float4(o8[0], o8[1], o8[2], o8[3]);
    *reinterpret_cast<float4*>(&dstRow[8 * tid + 4]) = make_float4(o8[4], o8[5], o8[6], o8[7]);
    idwt_chunk4(B, D1, 1024 + 4 * tid, thr, false, o8);
    *reinterpret_cast<float4*>(&dstRow[2048 + 8 * tid])     = make_float4(o8[0], o8[1], o8[2], o8[3]);
    *reinterpret_cast<float4*>(&dstRow[2048 + 8 * tid + 4]) = make_float4(o8[4], o8[5], o8[6], o8[7]);
    return;
  }

  // fused (af_c == false): reconstruct to registers, time-mask, noise, store.
  // w[0..7] = outputs 8t..8t+7 ; w[8..15] = outputs 2048+8t..2048+8t+7
  float w[16];
  idwt_chunk4(B, D1, 4 * tid, thr, false, w);
  idwt_chunk4(B, D1, 1024 + 4 * tid, thr, false, w + 8);
  if (at_c) {
    #pragma unroll
    for (int i = 0; i < 16; ++i) {
      int col = (i < 8) ? (8 * tid + i) : (2048 + 8 * tid + (i - 8));
      if (col >= t0_c && col < t0_c + 204) w[i] *= 0.1f;
    }
  }
  __syncthreads();
  float* red = B;
  float acc = 0.f;
  #pragma unroll
  for (int i = 0; i < 16; ++i) acc += w[i];
  red[tid] = acc; __syncthreads();
  for (int o = 128; o > 0; o >>= 1) { if (tid < o) red[tid] += red[tid + o]; __syncthreads(); }
  float nmu = red[0] * (1.0f / 4096.0f);
  __syncthreads();
  acc = 0.f;
  #pragma unroll
  for (int i = 0; i < 16; ++i) { float dv = w[i] - nmu; acc += dv * dv; }
  red[tid] = acc; __syncthreads();
  for (int o = 128; o > 0; o >>= 1) { if (tid < o) red[tid] += red[tid + o]; __syncthreads(); }
  float nsig = sqrtf(red[0] / 4095.0f);

  float ov[16];
  #pragma unroll
  for (int i = 0; i < 16; ++i) {
    uint32_t col = (uint32_t)((i < 8) ? (8 * tid + i) : (2048 + 8 * tid + (i - 8)));
    uint32_t idx = ((uint32_t)row << 12) + col;
    float z = jax_normal_from_bits(jbits_elem(kcx, kcy, idx));
    ov[i] = w[i] + __fmul_rn(__fmul_rn(z, 0.02f), nsig);
  }
  *reinterpret_cast<float4*>(&dstRow[8 * tid])            = make_float4(ov[0], ov[1], ov[2], ov[3]);
  *reinterpret_cast<float4*>(&dstRow[8 * tid + 4])        = make_float4(ov[4], ov[5], ov[6], ov[7]);
  *reinterpret_cast<float4*>(&dstRow[2048 + 8 * tid])     = make_float4(ov[8], ov[9], ov[10], ov[11]);
  *reinterpret_cast<float4*>(&dstRow[2048 + 8 * tid + 4]) = make_float4(ov[12], ov[13], ov[14], ov[15]);
}

// ---------------- RFFT-based distortion (2048-pt complex FFT) ---------------
__constant__ int c_STW2_OFF[5] = {0, 512, 640, 672, 680};

__device__ __forceinline__ int rev2048(int k) {
  return ((k & 3) << 9) | (((k >> 2) & 3) << 7) | (((k >> 4) & 3) << 5)
       | (((k >> 6) & 3) << 3) | (((k >> 8) & 3) << 1) | (k >> 10);
}

__device__ __forceinline__ float maskP(int K, int f0) {
  float m1 = (K >= f0 && K < f0 + 409) ? 0.1f : 1.0f;
  int K2 = (4096 - K) & 4095;
  float m2 = (K2 >= f0 && K2 < f0 + 409) ? 0.1f : 1.0f;
  return 0.5f * (m1 + m2);
}

__device__ __forceinline__ void retangle_one(int k, int f0,
    float zkr, float zki, float zmr, float zmi, float* outr, float* outi) {
  float xer = 0.5f * (zkr + zmr), xei = 0.5f * (zki - zmi);
  float xor_ = 0.5f * (zki + zmi), xoi = 0.5f * (zmr - zkr);
  float sn, cs;
  __sincosf((float)k * (-1.5339807878856412e-3f), &sn, &cs);
  float wxr = xor_ * cs - xoi * sn, wxi = xor_ * sn + xoi * cs;
  float X1r = xer + wxr, X1i = xei + wxi;
  float X2r = xer - wxr, X2i = xei - wxi;
  float m1 = maskP(k, f0), m2 = maskP(k + 2048, f0);
  X1r *= m1; X1i *= m1; X2r *= m2; X2i *= m2;
  float yer = 0.5f * (X1r + X2r), yei = 0.5f * (X1i + X2i);
  float dr = 0.5f * (X1r - X2r), di = 0.5f * (X1i - X2i);
  float yor = dr * cs + di * sn, yoi = di * cs - dr * sn;
  *outr = yer - yoi; *outi = yei + yor;
}

__device__ void distort_core(float* smem, const float4* v4, float* w,
                             int af, int f0, int at, int t0, int tid) {
  float* RE = smem;
  float* IM = smem + 2112;
  float2* STW = (float2*)(smem + 4224);
  if (af) {
    for (int t = tid; t < 682; t += 256) {
      int s, j;
      if (t < 512) { s = 0; j = t; }
      else if (t < 640) { s = 1; j = t - 512; }
      else if (t < 672) { s = 2; j = t - 640; }
      else if (t < 680) { s = 3; j = t - 672; }
      else { s = 4; j = t - 680; }
      int e = j << (2 * s);
      float ang = (float)e * (-3.0679615757712823e-3f);
      float sn, cs;
      __sincosf(ang, &sn, &cs);
      STW[t] = make_float2(cs, sn);
    }
    #pragma unroll
    for (int k = 0; k < 4; ++k) {
      int n = 2 * (tid + (k << 8));
      RE[PD(n)]     = v4[k].x; IM[PD(n)]     = v4[k].y;
      RE[PD(n + 1)] = v4[k].z; IM[PD(n + 1)] = v4[k].w;
    }
    __syncthreads();
    for (int s = 0; s < 5; ++s) {
      int Lsh = 11 - 2 * s, Qsh = Lsh - 2, Qm = (1 << Qsh) - 1, off = c_STW2_OFF[s];
      for (int b = tid; b < 512; b += 256) {
        int j = b & Qm, g = b >> Qsh;
        int i0 = (g << Lsh) + j;
        int i1 = i0 + (1 << Qsh), i2 = i1 + (1 << Qsh), i3 = i2 + (1 << Qsh);
        float x0r = RE[PD(i0)], x0i = IM[PD(i0)];
        float x1r = RE[PD(i1)], x1i = IM[PD(i1)];
        float x2r = RE[PD(i2)], x2i = IM[PD(i2)];
        float x3r = RE[PD(i3)], x3i = IM[PD(i3)];
        float t0r = x0r + x2r, t0i = x0i + x2i;
        float t1r = x0r - x2r, t1i = x0i - x2i;
        float t2r = x1r + x3r, t2i = x1i + x3i;
        float t3r = x1r - x3r, t3i = x1i - x3i;
        float2 w1 = STW[off + j];
        float c1 = w1.x, s1 = w1.y;
        float c2 = c1 * c1 - s1 * s1, s2 = 2.f * c1 * s1;
        float c3 = c1 * c2 - s1 * s2, s3 = c1 * s2 + s1 * c2;
        RE[PD(i0)] = t0r + t2r; IM[PD(i0)] = t0i + t2i;
        float u1r = t1r + t3i, u1i = t1i - t3r;
        RE[PD(i1)] = u1r * c1 - u1i * s1; IM[PD(i1)] = u1r * s1 + u1i * c1;
        float u2r = t0r - t2r, u2i = t0i - t2i;
        RE[PD(i2)] = u2r * c2 - u2i * s2; IM[PD(i2)] = u2r * s2 + u2i * c2;
        float u3r = t1r - t3i, u3i = t1i + t3r;
        RE[PD(i3)] = u3r * c3 - u3i * s3; IM[PD(i3)] = u3r * s3 + u3i * c3;
      }
      __syncthreads();
    }
    for (int m = tid; m < 1024; m += 256) {
      int i0 = 2 * m, i1 = 2 * m + 1;
      float ar = RE[PD(i0)], ai = IM[PD(i0)];
      float br = RE[PD(i1)], bi = IM[PD(i1)];
      RE[PD(i0)] = ar + br; IM[PD(i0)] = ai + bi;
      RE[PD(i1)] = ar - br; IM[PD(i1)] = ai - bi;
    }
    __syncthreads();
    for (int k0 = tid; k0 < 1024; k0 += 256) {
      if (k0 == 0) {
        {
          int pk = PD(rev2048(0));
          float zr = RE[pk], zi = IM[pk], orr, oi;
          retangle_one(0, f0, zr, zi, zr, zi, &orr, &oi);
          RE[pk] = orr; IM[pk] = oi;
        }
        {
          int pk = PD(rev2048(1024));
          float zr = RE[pk], zi = IM[pk], orr, oi;
          retangle_one(1024, f0, zr, zi, zr, zi, &orr, &oi);
          RE[pk] = orr; IM[pk] = oi;
        }
      } else {
        int m = 2048 - k0;
        int pk = PD(rev2048(k0)), pm = PD(rev2048(m));
        float zkr = RE[pk], zki = IM[pk];
        float zmr = RE[pm], zmi = IM[pm];
        float akr, aki, amr, ami;
        retangle_one(k0, f0, zkr, zki, zmr, zmi, &akr, &aki);
        retangle_one(m, f0, zmr, zmi, zkr, zki, &amr, &ami);
        RE[pk] = akr; IM[pk] = aki;
        RE[pm] = amr; IM[pm] = ami;
      }
    }
    __syncthreads();
    for (int m = tid; m < 1024; m += 256) {
      int i0 = 2 * m, i1 = 2 * m + 1;
      float ar = RE[PD(i0)], ai = IM[PD(i0)];
      float br = RE[PD(i1)], bi = IM[PD(i1)];
      RE[PD(i0)] = ar + br; IM[PD(i0)] = ai + bi;
      RE[PD(i1)] = ar - br; IM[PD(i1)] = ai - bi;
    }
    __syncthreads();
    for (int s = 4; s >= 0; --s) {
      int Lsh = 11 - 2 * s, Qsh = Lsh - 2, Qm = (1 << Qsh) - 1, off = c_STW2_OFF[s];
      for (int b = tid; b < 512; b += 256) {
        int j = b & Qm, g = b >> Qsh;
        int i0 = (g << Lsh) + j;
        int i1 = i0 + (1 << Qsh), i2 = i1 + (1 << Qsh), i3 = i2 + (1 << Qsh);
        float y0r = RE[PD(i0)], y0i = IM[PD(i0)];
        float y1r = RE[PD(i1)], y1i = IM[PD(i1)];
        float y2r = RE[PD(i2)], y2i = IM[PD(i2)];
        float y3r = RE[PD(i3)], y3i = IM[PD(i3)];
        float2 w1 = STW[off + j];
        float c1 = w1.x, s1 = -w1.y;
        float c2 = c1 * c1 - s1 * s1, s2 = 2.f * c1 * s1;
        float c3 = c1 * c2 - s1 * s2, s3 = c1 * s2 + s1 * c2;
        float z1r = y1r * c1 - y1i * s1, z1i = y1r * s1 + y1i * c1;
        float z2r = y2r * c2 - y2i * s2, z2i = y2r * s2 + y2i * c2;
        float z3r = y3r * c3 - y3i * s3, z3i = y3r * s3 + y3i * c3;
        float u0r = y0r + z2r, u0i = y0i + z2i;
        float u2r = y0r - z2r, u2i = y0i - z2i;
        float u1r = z1r + z3r, u1i = z1i + z3i;
        float u3r = z3i - z1i, u3i = z1r - z3r;
        RE[PD(i0)] = u0r + u1r; IM[PD(i0)] = u0i + u1i;
        RE[PD(i1)] = u2r + u3r; IM[PD(i1)] = u2i + u3i;
        RE[PD(i2)] = u0r - u1r; IM[PD(i2)] = u0i - u1i;
        RE[PD(i3)] = u2r - u3r; IM[PD(i3)] = u2i - u3i;
      }
      __syncthreads();
    }
    #pragma unroll
    for (int k = 0; k < 4; ++k) {
      int n = 2 * (tid + (k << 8));
      w[4 * k + 0] = RE[PD(n)]     * (1.0f / 2048.0f);
      w[4 * k + 1] = IM[PD(n)]     * (1.0f / 2048.0f);
      w[4 * k + 2] = RE[PD(n + 1)] * (1.0f / 2048.0f);
      w[4 * k + 3] = IM[PD(n + 1)] * (1.0f / 2048.0f);
    }
    __syncthreads();
  } else {
    #pragma unroll
    for (int k = 0; k < 4; ++k) {
      w[4 * k + 0] = v4[k].x; w[4 * k + 1] = v4[k].y;
      w[4 * k + 2] = v4[k].z; w[4 * k + 3] = v4[k].w;
    }
  }
  if (at) {
    #pragma unroll
    for (int i = 0; i < 16; ++i) {
      int col = 4 * (tid + ((i >> 2) << 8)) + (i & 3);
      if (col >= t0 && col < t0 + 204) w[i] *= 0.1f;
    }
  }
}

__global__ __launch_bounds__(256)
void distort_noise_kernel(const float* __restrict__ src, float* __restrict__ dst_d,
                          float* __restrict__ dst_n,
                          int af, int f0, int at, int t0, int nod, int wd,
                          uint32_t kx, uint32_t ky) {
  extern __shared__ float smem[];
  const int row = blockIdx.x, tid = threadIdx.x;

  const float4* s4 = reinterpret_cast<const float4*>(src + (size_t)row * T_LEN);
  float4 v4[4];
  #pragma unroll
  for (int k = 0; k < 4; ++k) v4[k] = s4[tid + (k << 8)];

  float w[16];
  distort_core(smem, v4, w, af, f0, at, t0, tid);

  if (wd) {
    float4* d4 = reinterpret_cast<float4*>(dst_d + (size_t)row * T_LEN);
    #pragma unroll
    for (int k = 0; k < 4; ++k)
      d4[tid + (k << 8)] = make_float4(w[4 * k], w[4 * k + 1], w[4 * k + 2], w[4 * k + 3]);
  }

  float nv[16];
  #pragma unroll
  for (int i = 0; i < 16; ++i) {
    float q;
    if (nod) q = w[i];
    else {
      float4 vv = v4[i >> 2];
      q = (i & 3) == 0 ? vv.x : (i & 3) == 1 ? vv.y : (i & 3) == 2 ? vv.z : vv.w;
    }
    nv[i] = q;
  }
  float* red = smem;
  float acc = 0.f;
  #pragma unroll
  for (int i = 0; i < 16; ++i) acc += nv[i];
  red[tid] = acc; __syncthreads();
  for (int o = 128; o > 0; o >>= 1) { if (tid < o) red[tid] += red[tid + o]; __syncthreads(); }
  float mu = red[0] * (1.0f / 4096.0f);
  __syncthreads();
  acc = 0.f;
  #pragma unroll
  for (int i = 0; i < 16; ++i) { float dv = nv[i] - mu; acc += dv * dv; }
  red[tid] = acc; __syncthreads();
  for (int o = 128; o > 0; o >>= 1) { if (tid < o) red[tid] += red[tid + o]; __syncthreads(); }
  float sigma = sqrtf(red[0] / 4095.0f);

  float4* n4 = reinterpret_cast<float4*>(dst_n + (size_t)row * T_LEN);
  #pragma unroll
  for (int k = 0; k < 4; ++k) {
    float o[4];
    #pragma unroll
    for (int c = 0; c < 4; ++c) {
      uint32_t col = (uint32_t)(4 * (tid + (k << 8)) + c);
      uint32_t idx = ((uint32_t)row << 12) + col;
      float z = jax_normal_from_bits(jbits_elem(kx, ky, idx));
      o[c] = nv[4 * k + c] + __fmul_rn(__fmul_rn(z, 0.02f), sigma);
    }
    n4[tid + (k << 8)] = make_float4(o[0], o[1], o[2], o[3]);
  }
}

// ---------------- launcher ----------------
extern "C" void kernel_launch(void* const* d_in, const int* in_sizes, int n_in,
                              void* d_out, int out_size, void* d_ws, size_t ws_size,
                              hipStream_t stream) {
  const float* x = (const float*)d_in[0];
  float* out = (float*)d_out;
  float* o0 = out;
  float* o1 = out + (size_t)N_ELEM;
  float* o2 = out + 2 * (size_t)N_ELEM;
  float* o3 = out + 3 * (size_t)N_ELEM;
  float* o4 = out + 4 * (size_t)N_ELEM;

  uint32_t r[8];
  jsplit4(0u, 42u, r);  // kd, kn, kcd, kcn
  int f0d, afd, t0d, atd, f0c, afc, t0c, atc;
  distort_params(r[0], r[1], &f0d, &afd, &t0d, &atd);
  distort_params(r[4], r[5], &f0c, &afc, &t0c, &atc);

  const size_t WAVE_LDS = 10012u * 4u;   // 40048 B -> 4 blocks/CU
  const size_t FFT_LDS  = 5588u * 4u;    // 22352 B -> 7 blocks/CU

  hipLaunchKernelGGL(wavelet_kernel, dim3(N_ROWS), dim3(256), WAVE_LDS, stream,
                     x, o0, o1, o4, afc ? 0 : 1, atc, t0c, r[6], r[7]);
  hipLaunchKernelGGL(distort_noise_kernel, dim3(N_ROWS), dim3(256),
                     afd ? FFT_LDS : 1024, stream,
                     x, o2, o3, afd, f0d, atd, t0d, 0, 1, r[2], r[3]);
  if (afc) {
    hipLaunchKernelGGL(distort_noise_kernel, dim3(N_ROWS), dim3(256), FFT_LDS, stream,
                       o4, o4, o4, 1, f0c, atc, t0c, 1, 0, r[6], r[7]);
  }
}

// Round 13
// 267.144 us; speedup vs baseline: 1.3453x; 1.0246x over previous
//
#include <hip/hip_runtime.h>
#include <stdint.h>

#define T_LEN 4096
#define N_ROWS 4096
#define N_ELEM (4096u * 4096u)
#define PD(i) ((i) + ((i) >> 5))

// ---------------- wavelet filters (db4) ----------------
__constant__ float c_DEC_LO[8] = {
  -0.010597401785069032f, 0.0328830116668852f, 0.030841381835560764f,
  -0.18703481171909309f, -0.027983769416859854f, 0.6308807679298589f,
   0.7148465705529157f, 0.2303778133088965f };
__constant__ float c_DEC_HI[8] = {
  -0.2303778133088965f, 0.7148465705529157f, -0.6308807679298589f,
  -0.027983769416859854f, 0.18703481171909309f, 0.030841381835560764f,
  -0.0328830116668852f, -0.010597401785069032f };

#define RL0 0.2303778133088965f
#define RL1 0.7148465705529157f
#define RL2 0.6308807679298589f
#define RL3 (-0.027983769416859854f)
#define RL4 (-0.18703481171909309f)
#define RL5 0.030841381835560764f
#define RL6 0.0328830116668852f
#define RL7 (-0.010597401785069032f)
#define RH0 (-0.010597401785069032f)
#define RH1 (-0.0328830116668852f)
#define RH2 0.030841381835560764f
#define RH3 0.18703481171909309f
#define RH4 (-0.027983769416859854f)
#define RH5 (-0.6308807679298589f)
#define RH6 0.7148465705529157f
#define RH7 (-0.2303778133088965f)

// ---------------- Threefry-2x32 (host+device) ----------------
__host__ __device__ __forceinline__ uint32_t rotl32(uint32_t v, int r) {
  return (v << r) | (v >> (32 - r));
}

__host__ __device__ __forceinline__ void tf2x32(uint32_t k0, uint32_t k1,
                                                uint32_t c0, uint32_t c1,
                                                uint32_t& o0, uint32_t& o1) {
  uint32_t ks2 = k0 ^ k1 ^ 0x1BD11BDAu;
  uint32_t x0 = c0 + k0;
  uint32_t x1 = c1 + k1;
#define TFR(r) { x0 += x1; x1 = rotl32(x1, r); x1 ^= x0; }
  TFR(13) TFR(15) TFR(26) TFR(6)
  x0 += k1;  x1 += ks2 + 1u;
  TFR(17) TFR(29) TFR(16) TFR(24)
  x0 += ks2; x1 += k0 + 2u;
  TFR(13) TFR(15) TFR(26) TFR(6)
  x0 += k0;  x1 += k1 + 3u;
  TFR(17) TFR(29) TFR(16) TFR(24)
  x0 += k1;  x1 += ks2 + 4u;
  TFR(13) TFR(15) TFR(26) TFR(6)
  x0 += ks2; x1 += k0 + 5u;
#undef TFR
  o0 = x0; o1 = x1;
}

__host__ __device__ __forceinline__ uint32_t jbits_scalar(uint32_t kx, uint32_t ky) {
  uint32_t a, b; tf2x32(kx, ky, 0u, 0u, a, b);
  return a ^ b;
}

__device__ __forceinline__ uint32_t jbits_elem(uint32_t kx, uint32_t ky, uint32_t i) {
  uint32_t a, b; tf2x32(kx, ky, 0u, i, a, b); return a ^ b;
}

__host__ __device__ __forceinline__ float junif_scalar(uint32_t kx, uint32_t ky) {
  union { uint32_t u; float f; } cv;
  cv.u = (jbits_scalar(kx, ky) >> 9) | 0x3f800000u;
  return cv.f - 1.0f;
}

__host__ __device__ __forceinline__ void jsplit2(uint32_t kx, uint32_t ky, uint32_t* o) {
  tf2x32(kx, ky, 0u, 0u, o[0], o[1]);
  tf2x32(kx, ky, 0u, 1u, o[2], o[3]);
}

__host__ __device__ __forceinline__ void jsplit4(uint32_t kx, uint32_t ky, uint32_t* o) {
  tf2x32(kx, ky, 0u, 0u, o[0], o[1]);
  tf2x32(kx, ky, 0u, 1u, o[2], o[3]);
  tf2x32(kx, ky, 0u, 2u, o[4], o[5]);
  tf2x32(kx, ky, 0u, 3u, o[6], o[7]);
}

__host__ __device__ __forceinline__ int jrandint(uint32_t kx, uint32_t ky, uint32_t span) {
  uint32_t c[4];
  jsplit2(kx, ky, c);
  uint32_t hi = jbits_scalar(c[0], c[1]);
  uint32_t lo = jbits_scalar(c[2], c[3]);
  uint32_t mult = 65536u % span;
  mult = (mult * mult) % span;
  uint32_t off = ((hi % span) * mult + (lo % span)) % span;
  return (int)off;
}

__host__ __device__ void distort_params(uint32_t kx, uint32_t ky,
                                        int* f0, int* af, int* t0, int* at) {
  uint32_t q[8];
  jsplit4(kx, ky, q);
  *af = junif_scalar(q[0], q[1]) < 0.3f;
  *f0 = jrandint(q[2], q[3], 3687u);
  *at = junif_scalar(q[4], q[5]) < 0.3f;
  *t0 = jrandint(q[6], q[7], 3892u);
}

__device__ __forceinline__ float erfinv32(float x) {
  float w = -log1pf(-x * x);
  float p;
  if (w < 5.0f) {
    w = w - 2.5f;
    p = 2.81022636e-08f;
    p = fmaf(p, w, 3.43273939e-07f);
    p = fmaf(p, w, -3.5233877e-06f);
    p = fmaf(p, w, -4.39150654e-06f);
    p = fmaf(p, w, 0.00021858087f);
    p = fmaf(p, w, -0.00125372503f);
    p = fmaf(p, w, -0.00417768164f);
    p = fmaf(p, w, 0.246640727f);
    p = fmaf(p, w, 1.50140941f);
  } else {
    w = sqrtf(w) - 3.0f;
    p = -0.000200214257f;
    p = fmaf(p, w, 0.000100950558f);
    p = fmaf(p, w, 0.00134934322f);
    p = fmaf(p, w, -0.00367342844f);
    p = fmaf(p, w, 0.00573950773f);
    p = fmaf(p, w, -0.0076224613f);
    p = fmaf(p, w, 0.00943887047f);
    p = fmaf(p, w, 1.00167406f);
    p = fmaf(p, w, 2.83297682f);
  }
  return p * x;
}

__device__ __forceinline__ float jax_normal_from_bits(uint32_t bits) {
  union { uint32_t u; float f; } cv;
  cv.u = (bits >> 9) | 0x3f800000u;
  float f = cv.f - 1.0f;
  const float lo = -0.99999994f;
  float u = __fadd_rn(__fmul_rn(f, 2.0f), lo);
  u = fmaxf(lo, u);
  return 1.41421356f * erfinv32(u);
}

// numpy tree-of-8 sum
__device__ __forceinline__ float tree8(const float* p) {
  return __fadd_rn(
      __fadd_rn(__fadd_rn(p[0], p[1]), __fadd_rn(p[2], p[3])),
      __fadd_rn(__fadd_rn(p[4], p[5]), __fadd_rn(p[6], p[7])));
}

// ---------------- wavelet primitives (per-output arithmetic bit-exact) -----
__device__ __forceinline__ void dwt_one(const float* a, int n, int i,
                                        float* oA, float* oD) {
  int base = 2 * i - 6;
  float pa[8], pd[8];
  #pragma unroll
  for (int j = 0; j < 8; ++j) {
    int q = base + j;
    q = (q < 0) ? (-q - 1) : ((q >= n) ? (2 * n - 1 - q) : q);
    float xv = a[q];
    pa[j] = __fmul_rn(c_DEC_LO[7 - j], xv);
    pd[j] = __fmul_rn(c_DEC_HI[7 - j], xv);
  }
  *oA = tree8(pa); *oD = tree8(pd);
}

__device__ __forceinline__ void dwt_chunk4(const float* a, int i0,
                                           float* oa, float* od) {
  const float4* ap = reinterpret_cast<const float4*>(a + 2 * i0 - 8);
  float4 v0 = ap[0], v1 = ap[1], v2 = ap[2], v3 = ap[3];
  float x[16] = {v0.x, v0.y, v0.z, v0.w, v1.x, v1.y, v1.z, v1.w,
                 v2.x, v2.y, v2.z, v2.w, v3.x, v3.y, v3.z, v3.w};
  float ra[4], rd[4];
  #pragma unroll
  for (int p = 0; p < 4; ++p) {
    float pa[8], pd[8];
    #pragma unroll
    for (int j = 0; j < 8; ++j) {
      float xv = x[2 * p + 2 + j];
      pa[j] = __fmul_rn(c_DEC_LO[7 - j], xv);
      pd[j] = __fmul_rn(c_DEC_HI[7 - j], xv);
    }
    ra[p] = tree8(pa); rd[p] = tree8(pd);
  }
  *reinterpret_cast<float4*>(&oa[i0]) = make_float4(ra[0], ra[1], ra[2], ra[3]);
  *reinterpret_cast<float4*>(&od[i0]) = make_float4(rd[0], rd[1], rd[2], rd[3]);
}

__device__ void dwt_step(const float* a, int n, float* oa, float* od,
                         int nOut, int tid) {
  int iHi = (n - 2) >> 1;
  int nPair = nOut >> 1;
  for (int u = tid; u < nPair; u += 256) {
    int i0 = 2 * u;
    if (u >= 2 && (i0 + 1) <= iHi) {
      int base = 2 * i0 - 6;
      float x[10];
      #pragma unroll
      for (int j = 0; j < 10; ++j) x[j] = a[base + j];
      float p0[8], p1[8], q0[8], q1[8];
      #pragma unroll
      for (int j = 0; j < 8; ++j) {
        p0[j] = __fmul_rn(c_DEC_LO[7 - j], x[j]);
        q0[j] = __fmul_rn(c_DEC_HI[7 - j], x[j]);
        p1[j] = __fmul_rn(c_DEC_LO[7 - j], x[j + 2]);
        q1[j] = __fmul_rn(c_DEC_HI[7 - j], x[j + 2]);
      }
      *reinterpret_cast<float2*>(&oa[i0]) = make_float2(tree8(p0), tree8(p1));
      *reinterpret_cast<float2*>(&od[i0]) = make_float2(tree8(q0), tree8(q1));
    } else {
      float a0, d0, a1, d1;
      dwt_one(a, n, i0, &a0, &d0);
      dwt_one(a, n, i0 + 1, &a1, &d1);
      oa[i0] = a0; od[i0] = d0;
      oa[i0 + 1] = a1; od[i0 + 1] = d1;
    }
  }
  for (int i = 2 * nPair + tid; i < nOut; i += 256) {
    float av, dv;
    dwt_one(a, n, i, &av, &dv);
    oa[i] = av; od[i] = dv;
  }
}

// core per-pair idwt math (bit-exact sequence; thresholds already applied)
__device__ __forceinline__ void idwt_core(float a0, float a1, float a2, float a3,
                                          float d0, float d1, float d2, float d3,
                                          float* ev, float* ov) {
  float saE = __fadd_rn(__fadd_rn(__fmul_rn(RL6, a0), __fmul_rn(RL4, a1)),
                        __fadd_rn(__fmul_rn(RL2, a2), __fmul_rn(RL0, a3)));
  float sdE = __fadd_rn(__fadd_rn(__fmul_rn(RH6, d0), __fmul_rn(RH4, d1)),
                        __fadd_rn(__fmul_rn(RH2, d2), __fmul_rn(RH0, d3)));
  float saO = __fadd_rn(__fadd_rn(__fmul_rn(RL7, a0), __fmul_rn(RL5, a1)),
                        __fadd_rn(__fmul_rn(RL3, a2), __fmul_rn(RL1, a3)));
  float sdO = __fadd_rn(__fadd_rn(__fmul_rn(RH7, d0), __fmul_rn(RH5, d1)),
                        __fadd_rn(__fmul_rn(RH3, d2), __fmul_rn(RH1, d3)));
  *ev = __fadd_rn(saE, sdE);
  *ov = __fadd_rn(saO, sdO);
}

#define TH(v, t) ((fabsf(v) < (t)) ? 0.f : (v))

// dual generic pair-level idwt: shared d loads, two variants
__device__ void idwt_dual_step(const float* __restrict__ a0b,
                               const float* __restrict__ a1b,
                               const float* __restrict__ d,
                               float* __restrict__ o0b, float* __restrict__ o1b,
                               int nOut, float thr0, float thr1, bool trA, int tid) {
  int nPair = nOut >> 1;
  for (int h = tid; h < nPair; h += 256) {
    float dd0 = d[h], dd1 = d[h + 1], dd2 = d[h + 2], dd3 = d[h + 3];
    {
      float a0 = a0b[h], a1 = a0b[h + 1], a2 = a0b[h + 2], a3 = a0b[h + 3];
      if (trA) { a0 = TH(a0, thr0); a1 = TH(a1, thr0); a2 = TH(a2, thr0); a3 = TH(a3, thr0); }
      float ev, ov;
      idwt_core(a0, a1, a2, a3, TH(dd0, thr0), TH(dd1, thr0), TH(dd2, thr0), TH(dd3, thr0), &ev, &ov);
      *reinterpret_cast<float2*>(&o0b[2 * h]) = make_float2(ev, ov);
    }
    {
      float a0 = a1b[h], a1 = a1b[h + 1], a2 = a1b[h + 2], a3 = a1b[h + 3];
      if (trA) { a0 = TH(a0, thr1); a1 = TH(a1, thr1); a2 = TH(a2, thr1); a3 = TH(a3, thr1); }
      float ev, ov;
      idwt_core(a0, a1, a2, a3, TH(dd0, thr1), TH(dd1, thr1), TH(dd2, thr1), TH(dd3, thr1), &ev, &ov);
      *reinterpret_cast<float2*>(&o1b[2 * h]) = make_float2(ev, ov);
    }
  }
  if (nOut & 1) {
    int h = nPair;
    if (tid == (h & 255)) {
      float dd0 = d[h], dd1 = d[h + 1], dd2 = d[h + 2], dd3 = d[h + 3];
      {
        float a0 = a0b[h], a1 = a0b[h + 1], a2 = a0b[h + 2], a3 = a0b[h + 3];
        if (trA) { a0 = TH(a0, thr0); a1 = TH(a1, thr0); a2 = TH(a2, thr0); a3 = TH(a3, thr0); }
        float ev, ov;
        idwt_core(a0, a1, a2, a3, TH(dd0, thr0), TH(dd1, thr0), TH(dd2, thr0), TH(dd3, thr0), &ev, &ov);
        o0b[2 * h] = ev;
      }
      {
        float a0 = a1b[h], a1 = a1b[h + 1], a2 = a1b[h + 2], a3 = a1b[h + 3];
        if (trA) { a0 = TH(a0, thr1); a1 = TH(a1, thr1); a2 = TH(a2, thr1); a3 = TH(a3, thr1); }
        float ev, ov;
        idwt_core(a0, a1, a2, a3, TH(dd0, thr1), TH(dd1, thr1), TH(dd2, thr1), TH(dd3, thr1), &ev, &ov);
        o1b[2 * h] = ev;
      }
    }
  }
}

// dual chunk: 4 pairs, shared d float4 loads, separate a per variant (trA=false)
__device__ __forceinline__ void idwt_dual_chunk4(const float* __restrict__ a0b,
                                                 const float* __restrict__ a1b,
                                                 const float* __restrict__ d,
                                                 int h0, float thr0, float thr1,
                                                 float* o8v0, float* o8v1) {
  float4 vd0 = *reinterpret_cast<const float4*>(d + h0);
  float4 vd1 = *reinterpret_cast<const float4*>(d + h0 + 4);
  float D8[8] = {vd0.x, vd0.y, vd0.z, vd0.w, vd1.x, vd1.y, vd1.z, vd1.w};
  {
    float4 va0 = *reinterpret_cast<const float4*>(a0b + h0);
    float4 va1 = *reinterpret_cast<const float4*>(a0b + h0 + 4);
    float A8[8] = {va0.x, va0.y, va0.z, va0.w, va1.x, va1.y, va1.z, va1.w};
    float T8[8];
    #pragma unroll
    for (int j = 0; j < 8; ++j) T8[j] = TH(D8[j], thr0);
    #pragma unroll
    for (int p = 0; p < 4; ++p) {
      idwt_core(A8[p], A8[p + 1], A8[p + 2], A8[p + 3],
                T8[p], T8[p + 1], T8[p + 2], T8[p + 3],
                &o8v0[2 * p], &o8v0[2 * p + 1]);
    }
  }
  {
    float4 va0 = *reinterpret_cast<const float4*>(a1b + h0);
    float4 va1 = *reinterpret_cast<const float4*>(a1b + h0 + 4);
    float A8[8] = {va0.x, va0.y, va0.z, va0.w, va1.x, va1.y, va1.z, va1.w};
    float T8[8];
    #pragma unroll
    for (int j = 0; j < 8; ++j) T8[j] = TH(D8[j], thr1);
    #pragma unroll
    for (int p = 0; p < 4; ++p) {
      idwt_core(A8[p], A8[p + 1], A8[p + 2], A8[p + 3],
                T8[p], T8[p + 1], T8[p + 2], T8[p + 3],
                &o8v1[2 * p], &o8v1[2 * p + 1]);
    }
  }
}

// single-variant boundary pair (for the 2051-level tail)
__device__ __forceinline__ void idwt_pair_vals(const float* __restrict__ a,
                                               const float* __restrict__ d,
                                               int h, float thr,
                                               float* ev, float* ov) {
  float a0 = a[h], a1 = a[h + 1], a2 = a[h + 2], a3 = a[h + 3];
  float d0 = TH(d[h], thr), d1 = TH(d[h + 1], thr);
  float d2 = TH(d[h + 2], thr), d3 = TH(d[h + 3], thr);
  idwt_core(a0, a1, a2, a3, d0, d1, d2, d3, ev, ov);
}

__device__ void np_pw262_partials(const float* src, float* pbuf, int tid) {
  if (tid < 24) {
    int blk = tid >> 3, k = tid & 7;
    const float* base = src + (blk == 0 ? 0 : (blk == 1 ? 128 : 192));
    int iters = (blk == 0 ? 16 : 8);
    float r = base[k];
    for (int it = 1; it < iters; ++it) r = __fadd_rn(r, base[8 * it + k]);
    pbuf[tid] = r;
  }
}

__device__ float np_pw262_combine(const float* src, const float* pbuf) {
  float b0 = tree8(pbuf + 0);
  float b1 = tree8(pbuf + 8);
  float b2 = tree8(pbuf + 16);
  for (int i = 256; i < 262; ++i) b2 = __fadd_rn(b2, src[i]);
  return __fadd_rn(b0, __fadd_rn(b1, b2));
}

// ---------------- wavelet kernel (o0, o1, o4[; fused mask+noise]) ----------
// LDS layout (floats): P[0:4116) | Q[4116:6180) | D1[6180:8232) | D2[8232:9264)
//   | D3[9264:9784) | D4[9784:10048) | SC[10048:10050) | Bp[10052:10076)
__global__ __launch_bounds__(256, 4)
void wavelet_kernel(const float* __restrict__ x, float* __restrict__ out0,
                    float* __restrict__ out1, float* __restrict__ out4,
                    int fuse, int at_c, int t0_c, uint32_t kcx, uint32_t kcy) {
  extern __shared__ float smem[];
  float* P  = smem;
  float* Q  = smem + 4116;
  float* D1 = smem + 6180;
  float* D2 = smem + 8232;
  float* D3 = smem + 9264;
  float* D4 = smem + 9784;
  float* SC = smem + 10048;
  float* Bp = smem + 10052;
  float* L3 = P + 1536;   // dwt3 lowpass (518)
  float* A4 = P + 2560;   // a4 (262)
  float* P0 = P;          // step2 v0 out (1030 region, 1029 valid)
  float* P1 = P + 1032;   // step2 v1 out
  float* Q0 = Q;          // step1 v0 out (518)
  float* Q1 = Q + 520;    // step1 v1 out
  float* V0 = Q;          // step3 v0 out (2051)
  float* V1 = P + 2064;   // step3 v1 out (2051)
  const int row = blockIdx.x, tid = threadIdx.x;
  const float4* s4 = reinterpret_cast<const float4*>(x + (size_t)row * T_LEN);
  float4* o04 = reinterpret_cast<float4*>(out0 + (size_t)row * T_LEN);
  #pragma unroll
  for (int k = 0; k < 4; ++k) {
    float4 v = s4[tid + (k << 8)];
    *reinterpret_cast<float4*>(&P[4 * (tid + (k << 8))]) = v;
    o04[tid + (k << 8)] = v;
  }
  __syncthreads();

  // ---- dwt level 1: P(4096) -> Q(2051), D1(2051) ----
  if (tid == 0) {
    #pragma unroll
    for (int i = 0; i < 4; ++i) {
      float av, dv; dwt_one(P, 4096, i, &av, &dv); Q[i] = av; D1[i] = dv;
    }
  } else {
    dwt_chunk4(P, 4 * tid, Q, D1);
  }
  dwt_chunk4(P, 1024 + 4 * tid, Q, D1);
  if (tid < 3) {
    float av, dv; dwt_one(P, 4096, 2048 + tid, &av, &dv);
    Q[2048 + tid] = av; D1[2048 + tid] = dv;
  }
  __syncthreads();

  // ---- dwt level 2: Q(2051) -> P(1029), D2(1029) ----
  if (tid == 0) {
    #pragma unroll
    for (int i = 0; i < 4; ++i) {
      float av, dv; dwt_one(Q, 2051, i, &av, &dv); P[i] = av; D2[i] = dv;
    }
  } else {
    dwt_chunk4(Q, 4 * tid, P, D2);
  }
  if (tid < 5) {
    float av, dv; dwt_one(Q, 2051, 1024 + tid, &av, &dv);
    P[1024 + tid] = av; D2[1024 + tid] = dv;
  }
  __syncthreads();

  // ---- dwt level 3: P(1029) -> L3(518), D3(518) ----
  dwt_step(P, 1029, L3, D3, 518, tid);  __syncthreads();
  // ---- dwt level 4: L3(518) -> A4(262), D4(262) ----
  dwt_step(L3, 518, A4, D4, 262, tid);  __syncthreads();

  // ---- sigma(a4), ddof=0, exact numpy pairwise order ----
  np_pw262_partials(A4, Bp, tid);
  __syncthreads();
  if (tid == 0) SC[0] = np_pw262_combine(A4, Bp) / 262.0f;
  __syncthreads();
  float mu = SC[0];
  for (int i = tid; i < 262; i += 256) {
    float dv = __fsub_rn(A4[i], mu);
    Q[i] = __fmul_rn(dv, dv);     // SQ overlay in Q (dwt1-lo dead)
  }
  __syncthreads();
  np_pw262_partials(Q, Bp, tid);
  __syncthreads();
  if (tid == 0) SC[1] = __fsqrt_rn(np_pw262_combine(Q, Bp) / 262.0f);
  __syncthreads();
  float sigma = SC[1];
  float thr0 = __fmul_rn(0.5f, sigma);   // -> out1
  float thr1 = __fmul_rn(0.25f, sigma);  // -> out4

  // ---- dual idwt chain ----
  // step1: a4(262) -> dual 518
  idwt_dual_step(A4, A4, D4, Q0, Q1, 518, thr0, thr1, true, tid);
  __syncthreads();
  // step2: dual 518 -> dual 1029
  idwt_dual_step(Q0, Q1, D3, P0, P1, 1029, thr0, thr1, false, tid);
  __syncthreads();
  // step3: dual 1029 -> dual 2051 (chunks + boundary)
  {
    float o80[8], o81[8];
    idwt_dual_chunk4(P0, P1, D2, 4 * tid, thr0, thr1, o80, o81);
    *reinterpret_cast<float4*>(&V0[8 * tid])     = make_float4(o80[0], o80[1], o80[2], o80[3]);
    *reinterpret_cast<float4*>(&V0[8 * tid + 4]) = make_float4(o80[4], o80[5], o80[6], o80[7]);
    *reinterpret_cast<float4*>(&V1[8 * tid])     = make_float4(o81[0], o81[1], o81[2], o81[3]);
    *reinterpret_cast<float4*>(&V1[8 * tid + 4]) = make_float4(o81[4], o81[5], o81[6], o81[7]);
    if (tid == 0) {
      float ev, ov;
      idwt_pair_vals(P0, D2, 1024, thr0, &ev, &ov);
      V0[2048] = ev; V0[2049] = ov;
      idwt_pair_vals(P1, D2, 1024, thr1, &ev, &ov);
      V1[2048] = ev; V1[2049] = ov;
    } else if (tid == 1) {
      float ev, ov;
      idwt_pair_vals(P0, D2, 1025, thr0, &ev, &ov);
      V0[2050] = ev;
      idwt_pair_vals(P1, D2, 1025, thr1, &ev, &ov);
      V1[2050] = ev;
    }
  }
  __syncthreads();

  // step4: dual 2051 -> 4096 each; v0 -> out1 global; v1 -> out4 (or fuse regs)
  float* o1Row = out1 + (size_t)row * T_LEN;
  float* o4Row = out4 + (size_t)row * T_LEN;
  float w[16];
  {
    float o80[8], o81[8];
    idwt_dual_chunk4(V0, V1, D1, 4 * tid, thr0, thr1, o80, o81);
    *reinterpret_cast<float4*>(&o1Row[8 * tid])     = make_float4(o80[0], o80[1], o80[2], o80[3]);
    *reinterpret_cast<float4*>(&o1Row[8 * tid + 4]) = make_float4(o80[4], o80[5], o80[6], o80[7]);
    #pragma unroll
    for (int j = 0; j < 8; ++j) w[j] = o81[j];
    idwt_dual_chunk4(V0, V1, D1, 1024 + 4 * tid, thr0, thr1, o80, o81);
    *reinterpret_cast<float4*>(&o1Row[2048 + 8 * tid])     = make_float4(o80[0], o80[1], o80[2], o80[3]);
    *reinterpret_cast<float4*>(&o1Row[2048 + 8 * tid + 4]) = make_float4(o80[4], o80[5], o80[6], o80[7]);
    #pragma unroll
    for (int j = 0; j < 8; ++j) w[8 + j] = o81[j];
  }
  if (!fuse) {
    *reinterpret_cast<float4*>(&o4Row[8 * tid])            = make_float4(w[0], w[1], w[2], w[3]);
    *reinterpret_cast<float4*>(&o4Row[8 * tid + 4])        = make_float4(w[4], w[5], w[6], w[7]);
    *reinterpret_cast<float4*>(&o4Row[2048 + 8 * tid])     = make_float4(w[8], w[9], w[10], w[11]);
    *reinterpret_cast<float4*>(&o4Row[2048 + 8 * tid + 4]) = make_float4(w[12], w[13], w[14], w[15]);
    return;
  }

  // fused (af_c == false): time-mask + additive noise on v1 reconstruction
  if (at_c) {
    #pragma unroll
    for (int i = 0; i < 16; ++i) {
      int col = (i < 8) ? (8 * tid + i) : (2048 + 8 * tid + (i - 8));
      if (col >= t0_c && col < t0_c + 204) w[i] *= 0.1f;
    }
  }
  __syncthreads();
  float* red = Q;
  float acc = 0.f;
  #pragma unroll
  for (int i = 0; i < 16; ++i) acc += w[i];
  red[tid] = acc; __syncthreads();
  for (int o = 128; o > 0; o >>= 1) { if (tid < o) red[tid] += red[tid + o]; __syncthreads(); }
  float nmu = red[0] * (1.0f / 4096.0f);
  __syncthreads();
  acc = 0.f;
  #pragma unroll
  for (int i = 0; i < 16; ++i) { float dv = w[i] - nmu; acc += dv * dv; }
  red[tid] = acc; __syncthreads();
  for (int o = 128; o > 0; o >>= 1) { if (tid < o) red[tid] += red[tid + o]; __syncthreads(); }
  float nsig = sqrtf(red[0] / 4095.0f);

  float ov[16];
  #pragma unroll
  for (int i = 0; i < 16; ++i) {
    uint32_t col = (uint32_t)((i < 8) ? (8 * tid + i) : (2048 + 8 * tid + (i - 8)));
    uint32_t idx = ((uint32_t)row << 12) + col;
    float z = jax_normal_from_bits(jbits_elem(kcx, kcy, idx));
    ov[i] = w[i] + __fmul_rn(__fmul_rn(z, 0.02f), nsig);
  }
  *reinterpret_cast<float4*>(&o4Row[8 * tid])            = make_float4(ov[0], ov[1], ov[2], ov[3]);
  *reinterpret_cast<float4*>(&o4Row[8 * tid + 4])        = make_float4(ov[4], ov[5], ov[6], ov[7]);
  *reinterpret_cast<float4*>(&o4Row[2048 + 8 * tid])     = make_float4(ov[8], ov[9], ov[10], ov[11]);
  *reinterpret_cast<float4*>(&o4Row[2048 + 8 * tid + 4]) = make_float4(ov[12], ov[13], ov[14], ov[15]);
}

// ---------------- RFFT-based distortion (2048-pt complex FFT) ---------------
__constant__ int c_STW2_OFF[5] = {0, 512, 640, 672, 680};

__device__ __forceinline__ int rev2048(int k) {
  return ((k & 3) << 9) | (((k >> 2) & 3) << 7) | (((k >> 4) & 3) << 5)
       | (((k >> 6) & 3) << 3) | (((k >> 8) & 3) << 1) | (k >> 10);
}

__device__ __forceinline__ float maskP(int K, int f0) {
  float m1 = (K >= f0 && K < f0 + 409) ? 0.1f : 1.0f;
  int K2 = (4096 - K) & 4095;
  float m2 = (K2 >= f0 && K2 < f0 + 409) ? 0.1f : 1.0f;
  return 0.5f * (m1 + m2);
}

__device__ __forceinline__ void retangle_one(int k, int f0,
    float zkr, float zki, float zmr, float zmi, float* outr, float* outi) {
  float xer = 0.5f * (zkr + zmr), xei = 0.5f * (zki - zmi);
  float xor_ = 0.5f * (zki + zmi), xoi = 0.5f * (zmr - zkr);
  float sn, cs;
  __sincosf((float)k * (-1.5339807878856412e-3f), &sn, &cs);
  float wxr = xor_ * cs - xoi * sn, wxi = xor_ * sn + xoi * cs;
  float X1r = xer + wxr, X1i = xei + wxi;
  float X2r = xer - wxr, X2i = xei - wxi;
  float m1 = maskP(k, f0), m2 = maskP(k + 2048, f0);
  X1r *= m1; X1i *= m1; X2r *= m2; X2i *= m2;
  float yer = 0.5f * (X1r + X2r), yei = 0.5f * (X1i + X2i);
  float dr = 0.5f * (X1r - X2r), di = 0.5f * (X1i - X2i);
  float yor = dr * cs + di * sn, yoi = di * cs - dr * sn;
  *outr = yer - yoi; *outi = yei + yor;
}

__device__ void distort_core(float* smem, const float4* v4, float* w,
                             int af, int f0, int at, int t0, int tid) {
  float* RE = smem;
  float* IM = smem + 2112;
  float2* STW = (float2*)(smem + 4224);
  if (af) {
    for (int t = tid; t < 682; t += 256) {
      int s, j;
      if (t < 512) { s = 0; j = t; }
      else if (t < 640) { s = 1; j = t - 512; }
      else if (t < 672) { s = 2; j = t - 640; }
      else if (t < 680) { s = 3; j = t - 672; }
      else { s = 4; j = t - 680; }
      int e = j << (2 * s);
      float ang = (float)e * (-3.0679615757712823e-3f);
      float sn, cs;
      __sincosf(ang, &sn, &cs);
      STW[t] = make_float2(cs, sn);
    }
    #pragma unroll
    for (int k = 0; k < 4; ++k) {
      int n = 2 * (tid + (k << 8));
      RE[PD(n)]     = v4[k].x; IM[PD(n)]     = v4[k].y;
      RE[PD(n + 1)] = v4[k].z; IM[PD(n + 1)] = v4[k].w;
    }
    __syncthreads();
    for (int s = 0; s < 5; ++s) {
      int Lsh = 11 - 2 * s, Qsh = Lsh - 2, Qm = (1 << Qsh) - 1, off = c_STW2_OFF[s];
      for (int b = tid; b < 512; b += 256) {
        int j = b & Qm, g = b >> Qsh;
        int i0 = (g << Lsh) + j;
        int i1 = i0 + (1 << Qsh), i2 = i1 + (1 << Qsh), i3 = i2 + (1 << Qsh);
        float x0r = RE[PD(i0)], x0i = IM[PD(i0)];
        float x1r = RE[PD(i1)], x1i = IM[PD(i1)];
        float x2r = RE[PD(i2)], x2i = IM[PD(i2)];
        float x3r = RE[PD(i3)], x3i = IM[PD(i3)];
        float t0r = x0r + x2r, t0i = x0i + x2i;
        float t1r = x0r - x2r, t1i = x0i - x2i;
        float t2r = x1r + x3r, t2i = x1i + x3i;
        float t3r = x1r - x3r, t3i = x1i - x3i;
        float2 w1 = STW[off + j];
        float c1 = w1.x, s1 = w1.y;
        float c2 = c1 * c1 - s1 * s1, s2 = 2.f * c1 * s1;
        float c3 = c1 * c2 - s1 * s2, s3 = c1 * s2 + s1 * c2;
        RE[PD(i0)] = t0r + t2r; IM[PD(i0)] = t0i + t2i;
        float u1r = t1r + t3i, u1i = t1i - t3r;
        RE[PD(i1)] = u1r * c1 - u1i * s1; IM[PD(i1)] = u1r * s1 + u1i * c1;
        float u2r = t0r - t2r, u2i = t0i - t2i;
        RE[PD(i2)] = u2r * c2 - u2i * s2; IM[PD(i2)] = u2r * s2 + u2i * c2;
        float u3r = t1r - t3i, u3i = t1i + t3r;
        RE[PD(i3)] = u3r * c3 - u3i * s3; IM[PD(i3)] = u3r * s3 + u3i * c3;
      }
      __syncthreads();
    }
    for (int m = tid; m < 1024; m += 256) {
      int i0 = 2 * m, i1 = 2 * m + 1;
      float ar = RE[PD(i0)], ai = IM[PD(i0)];
      float br = RE[PD(i1)], bi = IM[PD(i1)];
      RE[PD(i0)] = ar + br; IM[PD(i0)] = ai + bi;
      RE[PD(i1)] = ar - br; IM[PD(i1)] = ai - bi;
    }
    __syncthreads();
    for (int k0 = tid; k0 < 1024; k0 += 256) {
      if (k0 == 0) {
        {
          int pk = PD(rev2048(0));
          float zr = RE[pk], zi = IM[pk], orr, oi;
          retangle_one(0, f0, zr, zi, zr, zi, &orr, &oi);
          RE[pk] = orr; IM[pk] = oi;
        }
        {
          int pk = PD(rev2048(1024));
          float zr = RE[pk], zi = IM[pk], orr, oi;
          retangle_one(1024, f0, zr, zi, zr, zi, &orr, &oi);
          RE[pk] = orr; IM[pk] = oi;
        }
      } else {
        int m = 2048 - k0;
        int pk = PD(rev2048(k0)), pm = PD(rev2048(m));
        float zkr = RE[pk], zki = IM[pk];
        float zmr = RE[pm], zmi = IM[pm];
        float akr, aki, amr, ami;
        retangle_one(k0, f0, zkr, zki, zmr, zmi, &akr, &aki);
        retangle_one(m, f0, zmr, zmi, zkr, zki, &amr, &ami);
        RE[pk] = akr; IM[pk] = aki;
        RE[pm] = amr; IM[pm] = ami;
      }
    }
    __syncthreads();
    for (int m = tid; m < 1024; m += 256) {
      int i0 = 2 * m, i1 = 2 * m + 1;
      float ar = RE[PD(i0)], ai = IM[PD(i0)];
      float br = RE[PD(i1)], bi = IM[PD(i1)];
      RE[PD(i0)] = ar + br; IM[PD(i0)] = ai + bi;
      RE[PD(i1)] = ar - br; IM[PD(i1)] = ai - bi;
    }
    __syncthreads();
    for (int s = 4; s >= 0; --s) {
      int Lsh = 11 - 2 * s, Qsh = Lsh - 2, Qm = (1 << Qsh) - 1, off = c_STW2_OFF[s];
      for (int b = tid; b < 512; b += 256) {
        int j = b & Qm, g = b >> Qsh;
        int i0 = (g << Lsh) + j;
        int i1 = i0 + (1 << Qsh), i2 = i1 + (1 << Qsh), i3 = i2 + (1 << Qsh);
        float y0r = RE[PD(i0)], y0i = IM[PD(i0)];
        float y1r = RE[PD(i1)], y1i = IM[PD(i1)];
        float y2r = RE[PD(i2)], y2i = IM[PD(i2)];
        float y3r = RE[PD(i3)], y3i = IM[PD(i3)];
        float2 w1 = STW[off + j];
        float c1 = w1.x, s1 = -w1.y;
        float c2 = c1 * c1 - s1 * s1, s2 = 2.f * c1 * s1;
        float c3 = c1 * c2 - s1 * s2, s3 = c1 * s2 + s1 * c2;
        float z1r = y1r * c1 - y1i * s1, z1i = y1r * s1 + y1i * c1;
        float z2r = y2r * c2 - y2i * s2, z2i = y2r * s2 + y2i * c2;
        float z3r = y3r * c3 - y3i * s3, z3i = y3r * s3 + y3i * c3;
        float u0r = y0r + z2r, u0i = y0i + z2i;
        float u2r = y0r - z2r, u2i = y0i - z2i;
        float u1r = z1r + z3r, u1i = z1i + z3i;
        float u3r = z3i - z1i, u3i = z1r - z3r;
        RE[PD(i0)] = u0r + u1r; IM[PD(i0)] = u0i + u1i;
        RE[PD(i1)] = u2r + u3r; IM[PD(i1)] = u2i + u3i;
        RE[PD(i2)] = u0r - u1r; IM[PD(i2)] = u0i - u1i;
        RE[PD(i3)] = u2r - u3r; IM[PD(i3)] = u2i - u3i;
      }
      __syncthreads();
    }
    #pragma unroll
    for (int k = 0; k < 4; ++k) {
      int n = 2 * (tid + (k << 8));
      w[4 * k + 0] = RE[PD(n)]     * (1.0f / 2048.0f);
      w[4 * k + 1] = IM[PD(n)]     * (1.0f / 2048.0f);
      w[4 * k + 2] = RE[PD(n + 1)] * (1.0f / 2048.0f);
      w[4 * k + 3] = IM[PD(n + 1)] * (1.0f / 2048.0f);
    }
    __syncthreads();
  } else {
    #pragma unroll
    for (int k = 0; k < 4; ++k) {
      w[4 * k + 0] = v4[k].x; w[4 * k + 1] = v4[k].y;
      w[4 * k + 2] = v4[k].z; w[4 * k + 3] = v4[k].w;
    }
  }
  if (at) {
    #pragma unroll
    for (int i = 0; i < 16; ++i) {
      int col = 4 * (tid + ((i >> 2) << 8)) + (i & 3);
      if (col >= t0 && col < t0 + 204) w[i] *= 0.1f;
    }
  }
}

__global__ __launch_bounds__(256)
void distort_noise_kernel(const float* __restrict__ src, float* __restrict__ dst_d,
                          float* __restrict__ dst_n,
                          int af, int f0, int at, int t0, int nod, int wd,
                          uint32_t kx, uint32_t ky) {
  extern __shared__ float smem[];
  const int row = blockIdx.x, tid = threadIdx.x;

  const float4* s4 = reinterpret_cast<const float4*>(src + (size_t)row * T_LEN);
  float4 v4[4];
  #pragma unroll
  for (int k = 0; k < 4; ++k) v4[k] = s4[tid + (k << 8)];

  float w[16];
  distort_core(smem, v4, w, af, f0, at, t0, tid);

  if (wd) {
    float4* d4 = reinterpret_cast<float4*>(dst_d + (size_t)row * T_LEN);
    #pragma unroll
    for (int k = 0; k < 4; ++k)
      d4[tid + (k << 8)] = make_float4(w[4 * k], w[4 * k + 1], w[4 * k + 2], w[4 * k + 3]);
  }

  float nv[16];
  #pragma unroll
  for (int i = 0; i < 16; ++i) {
    float q;
    if (nod) q = w[i];
    else {
      float4 vv = v4[i >> 2];
      q = (i & 3) == 0 ? vv.x : (i & 3) == 1 ? vv.y : (i & 3) == 2 ? vv.z : vv.w;
    }
    nv[i] = q;
  }
  float* red = smem;
  float acc = 0.f;
  #pragma unroll
  for (int i = 0; i < 16; ++i) acc += nv[i];
  red[tid] = acc; __syncthreads();
  for (int o = 128; o > 0; o >>= 1) { if (tid < o) red[tid] += red[tid + o]; __syncthreads(); }
  float mu = red[0] * (1.0f / 4096.0f);
  __syncthreads();
  acc = 0.f;
  #pragma unroll
  for (int i = 0; i < 16; ++i) { float dv = nv[i] - mu; acc += dv * dv; }
  red[tid] = acc; __syncthreads();
  for (int o = 128; o > 0; o >>= 1) { if (tid < o) red[tid] += red[tid + o]; __syncthreads(); }
  float sigma = sqrtf(red[0] / 4095.0f);

  float4* n4 = reinterpret_cast<float4*>(dst_n + (size_t)row * T_LEN);
  #pragma unroll
  for (int k = 0; k < 4; ++k) {
    float o[4];
    #pragma unroll
    for (int c = 0; c < 4; ++c) {
      uint32_t col = (uint32_t)(4 * (tid + (k << 8)) + c);
      uint32_t idx = ((uint32_t)row << 12) + col;
      float z = jax_normal_from_bits(jbits_elem(kx, ky, idx));
      o[c] = nv[4 * k + c] + __fmul_rn(__fmul_rn(z, 0.02f), sigma);
    }
    n4[tid + (k << 8)] = make_float4(o[0], o[1], o[2], o[3]);
  }
}

// ---------------- launcher ----------------
extern "C" void kernel_launch(void* const* d_in, const int* in_sizes, int n_in,
                              void* d_out, int out_size, void* d_ws, size_t ws_size,
                              hipStream_t stream) {
  const float* x = (const float*)d_in[0];
  float* out = (float*)d_out;
  float* o0 = out;
  float* o1 = out + (size_t)N_ELEM;
  float* o2 = out + 2 * (size_t)N_ELEM;
  float* o3 = out + 3 * (size_t)N_ELEM;
  float* o4 = out + 4 * (size_t)N_ELEM;

  uint32_t r[8];
  jsplit4(0u, 42u, r);  // kd, kn, kcd, kcn
  int f0d, afd, t0d, atd, f0c, afc, t0c, atc;
  distort_params(r[0], r[1], &f0d, &afd, &t0d, &atd);
  distort_params(r[4], r[5], &f0c, &afc, &t0c, &atc);

  const size_t WAVE_LDS = 10076u * 4u;   // 40304 B -> 4 blocks/CU
  const size_t FFT_LDS  = 5588u * 4u;    // 22352 B -> 7 blocks/CU

  hipLaunchKernelGGL(wavelet_kernel, dim3(N_ROWS), dim3(256), WAVE_LDS, stream,
                     x, o0, o1, o4, afc ? 0 : 1, atc, t0c, r[6], r[7]);
  hipLaunchKernelGGL(distort_noise_kernel, dim3(N_ROWS), dim3(256),
                     afd ? FFT_LDS : 1024, stream,
                     x, o2, o3, afd, f0d, atd, t0d, 0, 1, r[2], r[3]);
  if (afc) {
    hipLaunchKernelGGL(distort_noise_kernel, dim3(N_ROWS), dim3(256), FFT_LDS, stream,
                       o4, o4, o4, 1, f0c, atc, t0c, 1, 0, r[6], r[7]);
  }
}